// Round 8
// baseline (1692.005 us; speedup 1.0000x reference)
//
#include <hip/hip_runtime.h>

typedef unsigned short ushort_t;
typedef _Float16 f16x8 __attribute__((ext_vector_type(8)));
typedef float f32x4 __attribute__((ext_vector_type(4)));
typedef unsigned short u16x8 __attribute__((ext_vector_type(8)));

#define DEVINL __device__ __forceinline__

constexpr int B = 16, S = 512, F = 1024;
constexpr int M_ROWS = B * S;                    // 8192
constexpr size_t NX = (size_t)M_ROWS * F;        // 8,388,608 elems per modality
constexpr size_t NW = (size_t)F * (2 * F);       // 2,097,152 elems per branch
constexpr size_t NSC = (size_t)3 * B * S * S;    // 12,582,912 score elems

// packed pitch for split-x: per row, chunk c holds 32 hi at c*64, 32 lo at c*64+32
constexpr int XP = 2 * F;        // 2048

// ---------- fp16 helpers ----------
DEVINL ushort_t f2h(float f) { return __builtin_bit_cast(ushort_t, (_Float16)f); }
DEVINL float h2f(ushort_t h) { return (float)__builtin_bit_cast(_Float16, h); }
DEVINL size_t pk(int row, int k, int pitch) {
  return (size_t)row * pitch + ((k >> 5) * 64) + (k & 31);
}

// ---------- async global->LDS (16B per lane) ----------
DEVINL void gload_lds16(const void* g, void* l) {
  __builtin_amdgcn_global_load_lds(
      (__attribute__((address_space(1))) void*)(g),
      (__attribute__((address_space(3))) void*)(l), 16, 0, 0);
}

DEVINL f32x4 mfma16h(f16x8 a, f16x8 b, f32x4 c) {
  return __builtin_amdgcn_mfma_f32_16x16x32_f16(a, b, c, 0, 0, 0);
}

// ================== barrier-light 256x256 GEMM core ==================
// C[256x256] = (Ah[+Al]) * B^T; A optionally 2-term fp16 Dekker split, B plain
// fp16 row-major [N][K]. 8 waves as 4M x 2N, wave-tile 64x128 = 4x8 frags of
// 16x16x32 f16, BK=32.
// NBUF=3: depth-2 prefetch, counted vmcnt(L) per step (L=loads/step). 1 blk/CU.
// NBUF=2: depth-1 prefetch, vmcnt(0) at step end — but issued a full MFMA
//   cluster (~1250 cyc) after the loads (> HBM 900), and the 32 KB/buffer LDS
//   footprint gives 2 blocks/CU so the sibling block covers stalls + barrier
//   convoy (m114 wave-level overlap).
// Race safety (both): a wave's lgkm-counted waits retire all its reads of
// buffer sb before its barrier; staging into sb is issued only after that
// barrier, so no wave can overwrite LDS another wave still needs.
template <int KSTEPS, int SPLIT_STEP, int TERMS, int KCHUNK, int NBUF>
DEVINL void gemm_core(const ushort_t* __restrict__ a1, const ushort_t* __restrict__ a2,
                      int lda, const ushort_t* __restrict__ bsrc, int ldb,
                      ushort_t* lds, int tid, f32x4 (&acc)[4][8]) {
  constexpr int BUFE = (TERMS == 2) ? 24576 : 16384;
  constexpr int ALO = 8192;
  constexpr int BOFF = (TERMS == 2) ? 16384 : 8192;
  constexpr int DEPTH = NBUF - 1;
  const int lane = tid & 63, w = tid >> 6;
  const int wr = (w >> 1) * 64, wc = (w & 1) * 128;
  // staging: lane -> row (l>>2), 16B slot (l&3) XOR-swizzled by (row>>1)&3 on
  // the GLOBAL source; LDS dest linear (both-sides-or-neither rule).
  const int scol = (((lane & 3) ^ ((lane >> 3) & 3)) * 8);
  const size_t grow = (size_t)(w * 32 + (lane >> 2));   // A and B both 256 rows
  // ds_read: row rb+(lane&15), logical slot lane>>4 -> phys ^((row>>1)&3)
  const int foff = (lane & 15) * 32 + (((lane >> 4) ^ ((lane >> 1) & 3)) * 8);

  auto stA = [&](int sb, int ks) {
    const ushort_t* base = (ks < SPLIT_STEP) ? a1 : a2;
    int kk = ks & (SPLIT_STEP - 1);
    const ushort_t* s = base + grow * lda + kk * KCHUNK + scol;
    ushort_t* dh = lds + sb * BUFE + w * 1024;
    gload_lds16(s, dh);
    gload_lds16(s + (size_t)16 * lda, dh + 512);
    if constexpr (TERMS == 2) {
      gload_lds16(s + 32, dh + ALO);                    // lo: same 128B line
      gload_lds16(s + 32 + (size_t)16 * lda, dh + ALO + 512);
    }
  };
  auto stB = [&](int sb, int ks) {
    const ushort_t* s = bsrc + grow * ldb + ks * 32 + scol;
    ushort_t* d = lds + sb * BUFE + BOFF + w * 1024;
    gload_lds16(s, d);
    gload_lds16(s + (size_t)16 * ldb, d + 512);
  };
  auto FR = [&](const ushort_t* rgn, int rb) -> f16x8 {
    return *(const f16x8*)(rgn + rb * 32 + foff);
  };
  auto VMW = [&]() {
    if constexpr (NBUF == 2)       asm volatile("s_waitcnt vmcnt(0)" ::: "memory");
    else if constexpr (TERMS == 2) asm volatile("s_waitcnt vmcnt(6)" ::: "memory");
    else                           asm volatile("s_waitcnt vmcnt(4)" ::: "memory");
  };

  // prologue: stage steps 0..DEPTH-1
#pragma unroll
  for (int d = 0; d < DEPTH; ++d) { stA(d, d); stB(d, d); }
  VMW();                                               // step 0 landed
  asm volatile("s_barrier" ::: "memory");

  for (int t = 0; t < KSTEPS; ++t) {
    const int cb = t % NBUF, sb = (t + DEPTH) % NBUF;
    const int ks = (t + DEPTH) & (KSTEPS - 1);         // clamped tail: uniform vmcnt
    stA(sb, ks); stB(sb, ks);                          // issue early (T14)
    const ushort_t* L = lds + cb * BUFE;
    f16x8 rAh[4], rAl[4], rB[8];
#pragma unroll
    for (int i = 0; i < 4; ++i) rAh[i] = FR(L, wr + i * 16);
#pragma unroll
    for (int j = 0; j < 8; ++j) rB[j] = FR(L + BOFF, wc + j * 16);
    if constexpr (TERMS == 2) {
#pragma unroll
      for (int i = 0; i < 4; ++i) rAl[i] = FR(L + ALO, wr + i * 16);
    }
    __builtin_amdgcn_s_setprio(1);
#pragma unroll
    for (int j = 0; j < 8; ++j)
#pragma unroll
      for (int i = 0; i < 4; ++i) acc[i][j] = mfma16h(rAh[i], rB[j], acc[i][j]);
    if constexpr (TERMS == 2) {
#pragma unroll
      for (int j = 0; j < 8; ++j)
#pragma unroll
        for (int i = 0; i < 4; ++i) acc[i][j] = mfma16h(rAl[i], rB[j], acc[i][j]);
    }
    __builtin_amdgcn_s_setprio(0);
    VMW();                                             // next step's loads landed
    asm volatile("s_barrier" ::: "memory");
  }
}

// ---------- kernel 1: split t/v/a -> packed fp16 hi|lo + transposed hi ----------
__global__ __launch_bounds__(256) void split_x_kernel(
    const float* __restrict__ v, const float* __restrict__ t, const float* __restrict__ a,
    ushort_t* __restrict__ xpack, ushort_t* __restrict__ xT) {
  __shared__ ushort_t tile[64][65];
  int mod = blockIdx.z;
  const float* src = (mod == 0) ? v : (mod == 1 ? t : a);
  int b = blockIdx.y;
  int s0 = (blockIdx.x >> 4) * 64;
  int f0 = (blockIdx.x & 15) * 64;
  int tid = threadIdx.x;
  ushort_t* xp = xpack + mod * (NX * 2);
  ushort_t* xt = xT + mod * NX;
  int fl = (tid & 15) * 4;
#pragma unroll
  for (int r = 0; r < 4; ++r) {
    int sl = (tid >> 4) + r * 16;
    int row = b * S + s0 + sl;
    float4 x = *(const float4*)(src + (size_t)row * F + f0 + fl);
    ushort_t h0 = f2h(x.x), h1 = f2h(x.y), h2 = f2h(x.z), h3 = f2h(x.w);
    size_t o = pk(row, f0 + fl, XP);
    *(ushort4*)(xp + o) = make_ushort4(h0, h1, h2, h3);
    *(ushort4*)(xp + o + 32) = make_ushort4(
        f2h(x.x - h2f(h0)), f2h(x.y - h2f(h1)),
        f2h(x.z - h2f(h2)), f2h(x.w - h2f(h3)));
    tile[sl][fl] = h0; tile[sl][fl + 1] = h1; tile[sl][fl + 2] = h2; tile[sl][fl + 3] = h3;
  }
  __syncthreads();
#pragma unroll
  for (int r = 0; r < 4; ++r) {
    int flr = (tid >> 4) + r * 16;
    int sl4 = (tid & 15) * 4;
    ushort4 o = make_ushort4(tile[sl4][flr], tile[sl4 + 1][flr],
                             tile[sl4 + 2][flr], tile[sl4 + 3][flr]);
    size_t tidx = ((size_t)(b * F + f0 + flr)) * S + s0 + sl4;
    *(ushort4*)(xt + tidx) = o;
  }
}

// ---------- kernel 2: W (2048x1024) -> WT plain fp16 (1024 rows x K=2048) ----------
__global__ __launch_bounds__(256) void split_w_kernel(
    const float* __restrict__ w0, const float* __restrict__ w1, const float* __restrict__ w2,
    ushort_t* __restrict__ wtpack) {
  __shared__ ushort_t th[64][65];
  int br = blockIdx.z;
  const float* w = (br == 0) ? w0 : (br == 1 ? w1 : w2);
  int g0 = blockIdx.x * 64;
  int f0 = blockIdx.y * 64;
  int tid = threadIdx.x;
  int gl = (tid & 15) * 4;
#pragma unroll
  for (int r = 0; r < 4; ++r) {
    int fl = (tid >> 4) + r * 16;
    float4 x = *(const float4*)(w + (size_t)(f0 + fl) * F + g0 + gl);
    th[fl][gl] = f2h(x.x); th[fl][gl + 1] = f2h(x.y);
    th[fl][gl + 2] = f2h(x.z); th[fl][gl + 3] = f2h(x.w);
  }
  __syncthreads();
  ushort_t* op = wtpack + br * NW;
#pragma unroll
  for (int r = 0; r < 4; ++r) {
    int glr = (tid >> 4) + r * 16;
    int fl4 = (tid & 15) * 4;
    size_t o = (size_t)(g0 + glr) * (2 * F) + f0 + fl4;
    *(ushort4*)(op + o) = make_ushort4(th[fl4][glr], th[fl4 + 1][glr],
                                       th[fl4 + 2][glr], th[fl4 + 3][glr]);
  }
}

// ---------- kernel 3: Feat = tanh(concat(x1,x2) @ W + b), fp16 out ----------
// TERMS=1 + NBUF=2: 64 KB LDS -> 2 blocks/CU co-resident.
__global__ __launch_bounds__(512, 4) void feat_gemm_kernel(
    const ushort_t* __restrict__ xpack, const ushort_t* __restrict__ wtpack,
    const float* __restrict__ b0, const float* __restrict__ b1, const float* __restrict__ b2,
    ushort_t* __restrict__ fpack) {
  constexpr int M1[3] = {1, 1, 2};   // t, t, a
  constexpr int M2[3] = {0, 2, 0};   // v, a, v
  __shared__ __attribute__((aligned(16))) ushort_t lds[2 * 16384];   // 64 KB
  int br = blockIdx.z;
  int lin = blockIdx.x;              // 0..127
  // XCD-chunked: lin&7 = XCD; the 4 gn-blocks sharing an A-panel-pair sit on
  // the SAME XCD (lin, +32, +64, +96 all have equal lin&7).
  int gm0 = ((lin & 7) * 4 + ((lin >> 3) & 3)) * 256;
  int gn0 = (lin >> 5) * 256;
  int tid = threadIdx.x, lane = tid & 63, w = tid >> 6;
  const ushort_t* a1 = xpack + M1[br] * (NX * 2) + (size_t)gm0 * XP;
  const ushort_t* a2 = xpack + M2[br] * (NX * 2) + (size_t)gm0 * XP;
  const ushort_t* bb = wtpack + br * NW + (size_t)gn0 * (2 * F);
  f32x4 acc[4][8] = {};
  gemm_core<64, 32, 1, 64, 2>(a1, a2, XP, bb, 2 * F, lds, tid, acc);
  const float* bias = (br == 0) ? b0 : (br == 1 ? b1 : b2);
  ushort_t* op = fpack + br * NX;
  int wr = (w >> 1) * 64, wc = (w & 1) * 128;
#pragma unroll
  for (int i = 0; i < 4; ++i)
#pragma unroll
    for (int j = 0; j < 8; ++j)
#pragma unroll
      for (int r = 0; r < 4; ++r) {
        int row = gm0 + wr + i * 16 + (lane >> 4) * 4 + r;
        int col = gn0 + wc + j * 16 + (lane & 15);
        op[(size_t)row * F + col] = f2h(tanhf(acc[i][j][r] + bias[col]));
      }
}

// ---------- kernel 4: scores = q @ feat^T, fp32 out (q kept 2-term split) ----------
__global__ __launch_bounds__(512, 2) void scores_gemm_kernel(
    const ushort_t* __restrict__ xpack, const ushort_t* __restrict__ fpack,
    float* __restrict__ scores) {
  constexpr int QM[3] = {2, 0, 1};   // a, v, t
  __shared__ __attribute__((aligned(16))) ushort_t lds[3 * 24576];   // 144 KB
  int z = blockIdx.z;
  int br = z >> 4, b = z & 15;
  int gm0 = blockIdx.x * 256;
  int gn0 = blockIdx.y * 256;
  int tid = threadIdx.x, lane = tid & 63, w = tid >> 6;
  const ushort_t* a1 = xpack + QM[br] * (NX * 2) + (size_t)(b * S + gm0) * XP;
  const ushort_t* bb = fpack + br * NX + (size_t)(b * S + gn0) * F;
  f32x4 acc[4][8] = {};
  gemm_core<32, 32, 2, 64, 3>(a1, a1, XP, bb, F, lds, tid, acc);
  float* out = scores + (size_t)z * S * S;
  int wr = (w >> 1) * 64, wc = (w & 1) * 128;
#pragma unroll
  for (int i = 0; i < 4; ++i)
#pragma unroll
    for (int j = 0; j < 8; ++j)
#pragma unroll
      for (int r = 0; r < 4; ++r) {
        int row = gm0 + wr + i * 16 + (lane >> 4) * 4 + r;
        int col = gn0 + wc + j * 16 + (lane & 15);
        out[(size_t)row * S + col] = acc[i][j][r];
      }
}

// ---------- kernel 5: row softmax (512), fp32 in -> fp16 p ----------
__global__ __launch_bounds__(256) void softmax_kernel(
    const float* __restrict__ scores, ushort_t* __restrict__ p) {
  int wave = threadIdx.x >> 6, lane = threadIdx.x & 63;
  int row = blockIdx.x * 4 + wave;
  const float* src = scores + (size_t)row * S;
  float4 v0 = *(const float4*)(src + lane * 8);
  float4 v1 = *(const float4*)(src + lane * 8 + 4);
  float m = fmaxf(fmaxf(fmaxf(v0.x, v0.y), fmaxf(v0.z, v0.w)),
                  fmaxf(fmaxf(v1.x, v1.y), fmaxf(v1.z, v1.w)));
#pragma unroll
  for (int d = 1; d < 64; d <<= 1) m = fmaxf(m, __shfl_xor(m, d));
  float e[8] = {expf(v0.x - m), expf(v0.y - m), expf(v0.z - m), expf(v0.w - m),
                expf(v1.x - m), expf(v1.y - m), expf(v1.z - m), expf(v1.w - m)};
  float s = ((e[0] + e[1]) + (e[2] + e[3])) + ((e[4] + e[5]) + (e[6] + e[7]));
#pragma unroll
  for (int d = 1; d < 64; d <<= 1) s += __shfl_xor(s, d);
  float inv = 1.0f / s;
  u16x8 o;
#pragma unroll
  for (int j = 0; j < 8; ++j) o[j] = f2h(e[j] * inv);
  *(u16x8*)(p + (size_t)row * S + lane * 8) = o;
}

// ---------- kernel 6: O = (p @ q) * feat, fp32 out ----------
// TERMS=1 + NBUF=2: 64 KB LDS -> 2 blocks/CU co-resident.
__global__ __launch_bounds__(512, 4) void pv_gemm_kernel(
    const ushort_t* __restrict__ p, const ushort_t* __restrict__ xT,
    const ushort_t* __restrict__ fpack, float* __restrict__ out) {
  constexpr int QM[3] = {2, 0, 1};
  __shared__ __attribute__((aligned(16))) ushort_t lds[2 * 16384];   // 64 KB
  int z = blockIdx.z;
  int br = z >> 4, b = z & 15;
  int gm0 = blockIdx.x * 256;
  int gn0 = blockIdx.y * 256;
  int tid = threadIdx.x, lane = tid & 63, w = tid >> 6;
  const ushort_t* pa = p + (size_t)z * S * S + (size_t)gm0 * S;
  const ushort_t* qt = xT + QM[br] * NX + (size_t)b * F * S + (size_t)gn0 * S;  // [f][s]
  f32x4 acc[4][8] = {};
  gemm_core<16, 16, 1, 32, 2>(pa, pa, S, qt, S, lds, tid, acc);
  const ushort_t* fp = fpack + br * NX;
  int wr = (w >> 1) * 64, wc = (w & 1) * 128;
#pragma unroll
  for (int i = 0; i < 4; ++i)
#pragma unroll
    for (int j = 0; j < 8; ++j)
#pragma unroll
      for (int r = 0; r < 4; ++r) {
        int row = gm0 + wr + i * 16 + (lane >> 4) * 4 + r;
        int col = gn0 + wc + j * 16 + (lane & 15);
        float fe = h2f(fp[(size_t)(b * S + row) * F + col]);
        out[(size_t)(b * S + row) * (3 * F) + br * F + col] = acc[i][j][r] * fe;
      }
}

extern "C" void kernel_launch(void* const* d_in, const int* in_sizes, int n_in,
                              void* d_out, int out_size, void* d_ws, size_t ws_size,
                              hipStream_t stream) {
  (void)in_sizes; (void)n_in; (void)out_size; (void)ws_size;
  const float* v = (const float*)d_in[0];
  const float* t = (const float*)d_in[1];
  const float* a = (const float*)d_in[2];
  const float* W_tv = (const float*)d_in[3];
  const float* b_tv = (const float*)d_in[4];
  const float* W_ta = (const float*)d_in[5];
  const float* b_ta = (const float*)d_in[6];
  const float* W_av = (const float*)d_in[7];
  const float* b_av = (const float*)d_in[8];
  float* out = (float*)d_out;

  // ws layout (~290 MB total)
  ushort_t* xpack = (ushort_t*)d_ws;            // 3 * NX*2 (fp16 hi|lo packed)
  ushort_t* xT = xpack + 3 * (NX * 2);          // 3 * NX (fp16 plain, [f][s])
  ushort_t* wtpack = xT + 3 * NX;               // 3 * NW (fp16 plain)
  ushort_t* fpack = wtpack + 3 * NW;            // 3 * NX (fp16 plain)
  float* scores = (float*)(fpack + 3 * NX);
  ushort_t* pbuf = (ushort_t*)(scores + NSC);

  split_x_kernel<<<dim3(128, 16, 3), 256, 0, stream>>>(v, t, a, xpack, xT);
  split_w_kernel<<<dim3(16, 32, 3), 256, 0, stream>>>(W_tv, W_ta, W_av, wtpack);
  feat_gemm_kernel<<<dim3(128, 1, 3), 512, 0, stream>>>(xpack, wtpack,
                                                        b_tv, b_ta, b_av, fpack);
  scores_gemm_kernel<<<dim3(2, 2, 48), 512, 0, stream>>>(xpack, fpack, scores);
  softmax_kernel<<<dim3((3 * B * S) / 4), 256, 0, stream>>>(scores, pbuf);
  pv_gemm_kernel<<<dim3(2, 4, 48), 512, 0, stream>>>(pbuf, xT, fpack, out);
}

// Round 9
// 349.170 us; speedup vs baseline: 4.8458x; 4.8458x over previous
//
#include <hip/hip_runtime.h>

typedef unsigned short ushort_t;
typedef _Float16 f16x8 __attribute__((ext_vector_type(8)));
typedef float f32x4 __attribute__((ext_vector_type(4)));
typedef unsigned short u16x8 __attribute__((ext_vector_type(8)));

#define DEVINL __device__ __forceinline__

constexpr int B = 16, S = 512, F = 1024;
constexpr int M_ROWS = B * S;                    // 8192
constexpr size_t NX = (size_t)M_ROWS * F;        // 8,388,608 elems per modality
constexpr size_t NW = (size_t)F * (2 * F);       // 2,097,152 elems per branch
constexpr size_t NSC = (size_t)3 * B * S * S;    // 12,582,912 score elems

// packed pitch for split-x: per row, chunk c holds 32 hi at c*64, 32 lo at c*64+32
constexpr int XP = 2 * F;        // 2048

// ---------- fp16 helpers ----------
DEVINL ushort_t f2h(float f) { return __builtin_bit_cast(ushort_t, (_Float16)f); }
DEVINL float h2f(ushort_t h) { return (float)__builtin_bit_cast(_Float16, h); }
DEVINL size_t pk(int row, int k, int pitch) {
  return (size_t)row * pitch + ((k >> 5) * 64) + (k & 31);
}

// ---------- async global->LDS (16B per lane) ----------
DEVINL void gload_lds16(const void* g, void* l) {
  __builtin_amdgcn_global_load_lds(
      (__attribute__((address_space(1))) void*)(g),
      (__attribute__((address_space(3))) void*)(l), 16, 0, 0);
}

DEVINL f32x4 mfma16h(f16x8 a, f16x8 b, f32x4 c) {
  return __builtin_amdgcn_mfma_f32_16x16x32_f16(a, b, c, 0, 0, 0);
}

// ================== barrier-light 256x256 GEMM core ==================
// C[256x256] = (Ah[+Al]) * B^T; A optionally 2-term fp16 Dekker split, B plain
// fp16 row-major [N][K]. 8 waves as 4M x 2N, wave-tile 64x128 = 4x8 frags of
// 16x16x32 f16, BK=32.
// NBUF=3: depth-2 prefetch, counted vmcnt(L) per step. 144 KB, 1 blk/CU.
// NBUF=2: depth-1 prefetch, vmcnt(0) at step end — issued a full MFMA cluster
//   (~1250 cyc) after the loads (> HBM 900); 64 KB LDS + VGPR<=128 gives
//   2 blocks/CU, sibling block covers stalls + barrier convoy (m114).
//   NOTE: do NOT raise __launch_bounds__ min-waves for this — (512,4) caps
//   VGPR at 64 and spills the 128-VGPR accumulator (R8: 3 GB scratch, 5x).
// Race safety (both): a wave's lgkm-counted waits retire all its reads of
// buffer sb before its barrier; staging into sb is issued only after that
// barrier, so no wave can overwrite LDS another wave still needs.
template <int KSTEPS, int SPLIT_STEP, int TERMS, int KCHUNK, int NBUF>
DEVINL void gemm_core(const ushort_t* __restrict__ a1, const ushort_t* __restrict__ a2,
                      int lda, const ushort_t* __restrict__ bsrc, int ldb,
                      ushort_t* lds, int tid, f32x4 (&acc)[4][8]) {
  constexpr int BUFE = (TERMS == 2) ? 24576 : 16384;
  constexpr int ALO = 8192;
  constexpr int BOFF = (TERMS == 2) ? 16384 : 8192;
  constexpr int DEPTH = NBUF - 1;
  const int lane = tid & 63, w = tid >> 6;
  const int wr = (w >> 1) * 64, wc = (w & 1) * 128;
  // staging: lane -> row (l>>2), 16B slot (l&3) XOR-swizzled by (row>>1)&3 on
  // the GLOBAL source; LDS dest linear (both-sides-or-neither rule).
  const int scol = (((lane & 3) ^ ((lane >> 3) & 3)) * 8);
  const size_t grow = (size_t)(w * 32 + (lane >> 2));   // A and B both 256 rows
  // ds_read: row rb+(lane&15), logical slot lane>>4 -> phys ^((row>>1)&3)
  const int foff = (lane & 15) * 32 + (((lane >> 4) ^ ((lane >> 1) & 3)) * 8);

  auto stA = [&](int sb, int ks) {
    const ushort_t* base = (ks < SPLIT_STEP) ? a1 : a2;
    int kk = ks & (SPLIT_STEP - 1);
    const ushort_t* s = base + grow * lda + kk * KCHUNK + scol;
    ushort_t* dh = lds + sb * BUFE + w * 1024;
    gload_lds16(s, dh);
    gload_lds16(s + (size_t)16 * lda, dh + 512);
    if constexpr (TERMS == 2) {
      gload_lds16(s + 32, dh + ALO);                    // lo: same 128B line
      gload_lds16(s + 32 + (size_t)16 * lda, dh + ALO + 512);
    }
  };
  auto stB = [&](int sb, int ks) {
    const ushort_t* s = bsrc + grow * ldb + ks * 32 + scol;
    ushort_t* d = lds + sb * BUFE + BOFF + w * 1024;
    gload_lds16(s, d);
    gload_lds16(s + (size_t)16 * ldb, d + 512);
  };
  auto FR = [&](const ushort_t* rgn, int rb) -> f16x8 {
    return *(const f16x8*)(rgn + rb * 32 + foff);
  };
  auto VMW = [&]() {
    if constexpr (NBUF == 2)       asm volatile("s_waitcnt vmcnt(0)" ::: "memory");
    else if constexpr (TERMS == 2) asm volatile("s_waitcnt vmcnt(6)" ::: "memory");
    else                           asm volatile("s_waitcnt vmcnt(4)" ::: "memory");
  };

  // prologue: stage steps 0..DEPTH-1
#pragma unroll
  for (int d = 0; d < DEPTH; ++d) { stA(d, d); stB(d, d); }
  VMW();                                               // step 0 landed
  asm volatile("s_barrier" ::: "memory");

  for (int t = 0; t < KSTEPS; ++t) {
    const int cb = t % NBUF, sb = (t + DEPTH) % NBUF;
    const int ks = (t + DEPTH) & (KSTEPS - 1);         // clamped tail: uniform vmcnt
    stA(sb, ks); stB(sb, ks);                          // issue early (T14)
    const ushort_t* L = lds + cb * BUFE;
    f16x8 rAh[4], rAl[4], rB[8];
#pragma unroll
    for (int i = 0; i < 4; ++i) rAh[i] = FR(L, wr + i * 16);
#pragma unroll
    for (int j = 0; j < 8; ++j) rB[j] = FR(L + BOFF, wc + j * 16);
    if constexpr (TERMS == 2) {
#pragma unroll
      for (int i = 0; i < 4; ++i) rAl[i] = FR(L + ALO, wr + i * 16);
    }
    __builtin_amdgcn_s_setprio(1);
#pragma unroll
    for (int j = 0; j < 8; ++j)
#pragma unroll
      for (int i = 0; i < 4; ++i) acc[i][j] = mfma16h(rAh[i], rB[j], acc[i][j]);
    if constexpr (TERMS == 2) {
#pragma unroll
      for (int j = 0; j < 8; ++j)
#pragma unroll
        for (int i = 0; i < 4; ++i) acc[i][j] = mfma16h(rAl[i], rB[j], acc[i][j]);
    }
    __builtin_amdgcn_s_setprio(0);
    VMW();                                             // next step's loads landed
    asm volatile("s_barrier" ::: "memory");
  }
}

// ---------- kernel 1: split t/v/a -> packed fp16 hi|lo + transposed hi ----------
__global__ __launch_bounds__(256) void split_x_kernel(
    const float* __restrict__ v, const float* __restrict__ t, const float* __restrict__ a,
    ushort_t* __restrict__ xpack, ushort_t* __restrict__ xT) {
  __shared__ ushort_t tile[64][65];
  int mod = blockIdx.z;
  const float* src = (mod == 0) ? v : (mod == 1 ? t : a);
  int b = blockIdx.y;
  int s0 = (blockIdx.x >> 4) * 64;
  int f0 = (blockIdx.x & 15) * 64;
  int tid = threadIdx.x;
  ushort_t* xp = xpack + mod * (NX * 2);
  ushort_t* xt = xT + mod * NX;
  int fl = (tid & 15) * 4;
#pragma unroll
  for (int r = 0; r < 4; ++r) {
    int sl = (tid >> 4) + r * 16;
    int row = b * S + s0 + sl;
    float4 x = *(const float4*)(src + (size_t)row * F + f0 + fl);
    ushort_t h0 = f2h(x.x), h1 = f2h(x.y), h2 = f2h(x.z), h3 = f2h(x.w);
    size_t o = pk(row, f0 + fl, XP);
    *(ushort4*)(xp + o) = make_ushort4(h0, h1, h2, h3);
    *(ushort4*)(xp + o + 32) = make_ushort4(
        f2h(x.x - h2f(h0)), f2h(x.y - h2f(h1)),
        f2h(x.z - h2f(h2)), f2h(x.w - h2f(h3)));
    tile[sl][fl] = h0; tile[sl][fl + 1] = h1; tile[sl][fl + 2] = h2; tile[sl][fl + 3] = h3;
  }
  __syncthreads();
#pragma unroll
  for (int r = 0; r < 4; ++r) {
    int flr = (tid >> 4) + r * 16;
    int sl4 = (tid & 15) * 4;
    ushort4 o = make_ushort4(tile[sl4][flr], tile[sl4 + 1][flr],
                             tile[sl4 + 2][flr], tile[sl4 + 3][flr]);
    size_t tidx = ((size_t)(b * F + f0 + flr)) * S + s0 + sl4;
    *(ushort4*)(xt + tidx) = o;
  }
}

// ---------- kernel 2: W (2048x1024) -> WT plain fp16 (1024 rows x K=2048) ----------
__global__ __launch_bounds__(256) void split_w_kernel(
    const float* __restrict__ w0, const float* __restrict__ w1, const float* __restrict__ w2,
    ushort_t* __restrict__ wtpack) {
  __shared__ ushort_t th[64][65];
  int br = blockIdx.z;
  const float* w = (br == 0) ? w0 : (br == 1 ? w1 : w2);
  int g0 = blockIdx.x * 64;
  int f0 = blockIdx.y * 64;
  int tid = threadIdx.x;
  int gl = (tid & 15) * 4;
#pragma unroll
  for (int r = 0; r < 4; ++r) {
    int fl = (tid >> 4) + r * 16;
    float4 x = *(const float4*)(w + (size_t)(f0 + fl) * F + g0 + gl);
    th[fl][gl] = f2h(x.x); th[fl][gl + 1] = f2h(x.y);
    th[fl][gl + 2] = f2h(x.z); th[fl][gl + 3] = f2h(x.w);
  }
  __syncthreads();
  ushort_t* op = wtpack + br * NW;
#pragma unroll
  for (int r = 0; r < 4; ++r) {
    int glr = (tid >> 4) + r * 16;
    int fl4 = (tid & 15) * 4;
    size_t o = (size_t)(g0 + glr) * (2 * F) + f0 + fl4;
    *(ushort4*)(op + o) = make_ushort4(th[fl4][glr], th[fl4 + 1][glr],
                                       th[fl4 + 2][glr], th[fl4 + 3][glr]);
  }
}

// ---------- kernel 3: Feat = tanh(concat(x1,x2) @ W + b), fp16 out ----------
// TERMS=1 + NBUF=2: 64 KB LDS + ~100 VGPR -> 2 blocks/CU WITHOUT launch-bounds
// coercion (R8 lesson: (512,4) caps VGPR at 64 -> accumulator spills).
__global__ __launch_bounds__(512, 2) void feat_gemm_kernel(
    const ushort_t* __restrict__ xpack, const ushort_t* __restrict__ wtpack,
    const float* __restrict__ b0, const float* __restrict__ b1, const float* __restrict__ b2,
    ushort_t* __restrict__ fpack) {
  constexpr int M1[3] = {1, 1, 2};   // t, t, a
  constexpr int M2[3] = {0, 2, 0};   // v, a, v
  __shared__ __attribute__((aligned(16))) ushort_t lds[2 * 16384];   // 64 KB
  int br = blockIdx.z;
  int lin = blockIdx.x;              // 0..127
  // XCD-chunked: lin&7 = XCD; the 4 gn-blocks sharing an A-panel-pair sit on
  // the SAME XCD (lin, +32, +64, +96 all have equal lin&7).
  int gm0 = ((lin & 7) * 4 + ((lin >> 3) & 3)) * 256;
  int gn0 = (lin >> 5) * 256;
  int tid = threadIdx.x, lane = tid & 63, w = tid >> 6;
  const ushort_t* a1 = xpack + M1[br] * (NX * 2) + (size_t)gm0 * XP;
  const ushort_t* a2 = xpack + M2[br] * (NX * 2) + (size_t)gm0 * XP;
  const ushort_t* bb = wtpack + br * NW + (size_t)gn0 * (2 * F);
  f32x4 acc[4][8] = {};
  gemm_core<64, 32, 1, 64, 2>(a1, a2, XP, bb, 2 * F, lds, tid, acc);
  const float* bias = (br == 0) ? b0 : (br == 1 ? b1 : b2);
  ushort_t* op = fpack + br * NX;
  int wr = (w >> 1) * 64, wc = (w & 1) * 128;
#pragma unroll
  for (int i = 0; i < 4; ++i)
#pragma unroll
    for (int j = 0; j < 8; ++j)
#pragma unroll
      for (int r = 0; r < 4; ++r) {
        int row = gm0 + wr + i * 16 + (lane >> 4) * 4 + r;
        int col = gn0 + wc + j * 16 + (lane & 15);
        op[(size_t)row * F + col] = f2h(tanhf(acc[i][j][r] + bias[col]));
      }
}

// ---------- kernel 4: scores = q @ feat^T, fp32 out (q kept 2-term split) ----------
__global__ __launch_bounds__(512, 2) void scores_gemm_kernel(
    const ushort_t* __restrict__ xpack, const ushort_t* __restrict__ fpack,
    float* __restrict__ scores) {
  constexpr int QM[3] = {2, 0, 1};   // a, v, t
  __shared__ __attribute__((aligned(16))) ushort_t lds[3 * 24576];   // 144 KB
  int z = blockIdx.z;
  int br = z >> 4, b = z & 15;
  int gm0 = blockIdx.x * 256;
  int gn0 = blockIdx.y * 256;
  int tid = threadIdx.x, lane = tid & 63, w = tid >> 6;
  const ushort_t* a1 = xpack + QM[br] * (NX * 2) + (size_t)(b * S + gm0) * XP;
  const ushort_t* bb = fpack + br * NX + (size_t)(b * S + gn0) * F;
  f32x4 acc[4][8] = {};
  gemm_core<32, 32, 2, 64, 3>(a1, a1, XP, bb, F, lds, tid, acc);
  float* out = scores + (size_t)z * S * S;
  int wr = (w >> 1) * 64, wc = (w & 1) * 128;
#pragma unroll
  for (int i = 0; i < 4; ++i)
#pragma unroll
    for (int j = 0; j < 8; ++j)
#pragma unroll
      for (int r = 0; r < 4; ++r) {
        int row = gm0 + wr + i * 16 + (lane >> 4) * 4 + r;
        int col = gn0 + wc + j * 16 + (lane & 15);
        out[(size_t)row * S + col] = acc[i][j][r];
      }
}

// ---------- kernel 5: row softmax (512), fp32 in -> fp16 p ----------
__global__ __launch_bounds__(256) void softmax_kernel(
    const float* __restrict__ scores, ushort_t* __restrict__ p) {
  int wave = threadIdx.x >> 6, lane = threadIdx.x & 63;
  int row = blockIdx.x * 4 + wave;
  const float* src = scores + (size_t)row * S;
  float4 v0 = *(const float4*)(src + lane * 8);
  float4 v1 = *(const float4*)(src + lane * 8 + 4);
  float m = fmaxf(fmaxf(fmaxf(v0.x, v0.y), fmaxf(v0.z, v0.w)),
                  fmaxf(fmaxf(v1.x, v1.y), fmaxf(v1.z, v1.w)));
#pragma unroll
  for (int d = 1; d < 64; d <<= 1) m = fmaxf(m, __shfl_xor(m, d));
  float e[8] = {expf(v0.x - m), expf(v0.y - m), expf(v0.z - m), expf(v0.w - m),
                expf(v1.x - m), expf(v1.y - m), expf(v1.z - m), expf(v1.w - m)};
  float s = ((e[0] + e[1]) + (e[2] + e[3])) + ((e[4] + e[5]) + (e[6] + e[7]));
#pragma unroll
  for (int d = 1; d < 64; d <<= 1) s += __shfl_xor(s, d);
  float inv = 1.0f / s;
  u16x8 o;
#pragma unroll
  for (int j = 0; j < 8; ++j) o[j] = f2h(e[j] * inv);
  *(u16x8*)(p + (size_t)row * S + lane * 8) = o;
}

// ---------- kernel 6: O = (p @ q) * feat, fp32 out ----------
// TERMS=1 + NBUF=2: 64 KB LDS -> 2 blocks/CU (natural occupancy, no coercion).
__global__ __launch_bounds__(512, 2) void pv_gemm_kernel(
    const ushort_t* __restrict__ p, const ushort_t* __restrict__ xT,
    const ushort_t* __restrict__ fpack, float* __restrict__ out) {
  constexpr int QM[3] = {2, 0, 1};
  __shared__ __attribute__((aligned(16))) ushort_t lds[2 * 16384];   // 64 KB
  int z = blockIdx.z;
  int br = z >> 4, b = z & 15;
  int gm0 = blockIdx.x * 256;
  int gn0 = blockIdx.y * 256;
  int tid = threadIdx.x, lane = tid & 63, w = tid >> 6;
  const ushort_t* pa = p + (size_t)z * S * S + (size_t)gm0 * S;
  const ushort_t* qt = xT + QM[br] * NX + (size_t)b * F * S + (size_t)gn0 * S;  // [f][s]
  f32x4 acc[4][8] = {};
  gemm_core<16, 16, 1, 32, 2>(pa, pa, S, qt, S, lds, tid, acc);
  const ushort_t* fp = fpack + br * NX;
  int wr = (w >> 1) * 64, wc = (w & 1) * 128;
#pragma unroll
  for (int i = 0; i < 4; ++i)
#pragma unroll
    for (int j = 0; j < 8; ++j)
#pragma unroll
      for (int r = 0; r < 4; ++r) {
        int row = gm0 + wr + i * 16 + (lane >> 4) * 4 + r;
        int col = gn0 + wc + j * 16 + (lane & 15);
        float fe = h2f(fp[(size_t)(b * S + row) * F + col]);
        out[(size_t)(b * S + row) * (3 * F) + br * F + col] = acc[i][j][r] * fe;
      }
}

extern "C" void kernel_launch(void* const* d_in, const int* in_sizes, int n_in,
                              void* d_out, int out_size, void* d_ws, size_t ws_size,
                              hipStream_t stream) {
  (void)in_sizes; (void)n_in; (void)out_size; (void)ws_size;
  const float* v = (const float*)d_in[0];
  const float* t = (const float*)d_in[1];
  const float* a = (const float*)d_in[2];
  const float* W_tv = (const float*)d_in[3];
  const float* b_tv = (const float*)d_in[4];
  const float* W_ta = (const float*)d_in[5];
  const float* b_ta = (const float*)d_in[6];
  const float* W_av = (const float*)d_in[7];
  const float* b_av = (const float*)d_in[8];
  float* out = (float*)d_out;

  // ws layout (~290 MB total)
  ushort_t* xpack = (ushort_t*)d_ws;            // 3 * NX*2 (fp16 hi|lo packed)
  ushort_t* xT = xpack + 3 * (NX * 2);          // 3 * NX (fp16 plain, [f][s])
  ushort_t* wtpack = xT + 3 * NX;               // 3 * NW (fp16 plain)
  ushort_t* fpack = wtpack + 3 * NW;            // 3 * NX (fp16 plain)
  float* scores = (float*)(fpack + 3 * NX);
  ushort_t* pbuf = (ushort_t*)(scores + NSC);

  split_x_kernel<<<dim3(128, 16, 3), 256, 0, stream>>>(v, t, a, xpack, xT);
  split_w_kernel<<<dim3(16, 32, 3), 256, 0, stream>>>(W_tv, W_ta, W_av, wtpack);
  feat_gemm_kernel<<<dim3(128, 1, 3), 512, 0, stream>>>(xpack, wtpack,
                                                        b_tv, b_ta, b_av, fpack);
  scores_gemm_kernel<<<dim3(2, 2, 48), 512, 0, stream>>>(xpack, fpack, scores);
  softmax_kernel<<<dim3((3 * B * S) / 4), 256, 0, stream>>>(scores, pbuf);
  pv_gemm_kernel<<<dim3(2, 4, 48), 512, 0, stream>>>(pbuf, xT, fpack, out);
}

// Round 10
// 337.469 us; speedup vs baseline: 5.0138x; 1.0347x over previous
//
#include <hip/hip_runtime.h>

typedef unsigned short ushort_t;
typedef _Float16 f16x8 __attribute__((ext_vector_type(8)));
typedef float f32x4 __attribute__((ext_vector_type(4)));
typedef unsigned short u16x8 __attribute__((ext_vector_type(8)));

#define DEVINL __device__ __forceinline__

constexpr int B = 16, S = 512, F = 1024;
constexpr int M_ROWS = B * S;                    // 8192
constexpr size_t NX = (size_t)M_ROWS * F;        // 8,388,608 elems per modality
constexpr size_t NW = (size_t)F * (2 * F);       // 2,097,152 elems per branch
constexpr size_t NSC = (size_t)3 * B * S * S;    // 12,582,912 score elems

// packed pitch for split-x: per row, chunk c holds 32 hi at c*64, 32 lo at c*64+32
constexpr int XP = 2 * F;        // 2048

// ---------- fp16 helpers ----------
DEVINL ushort_t f2h(float f) { return __builtin_bit_cast(ushort_t, (_Float16)f); }
DEVINL float h2f(ushort_t h) { return (float)__builtin_bit_cast(_Float16, h); }
DEVINL size_t pk(int row, int k, int pitch) {
  return (size_t)row * pitch + ((k >> 5) * 64) + (k & 31);
}

// ---------- async global->LDS (16B per lane) ----------
DEVINL void gload_lds16(const void* g, void* l) {
  __builtin_amdgcn_global_load_lds(
      (__attribute__((address_space(1))) void*)(g),
      (__attribute__((address_space(3))) void*)(l), 16, 0, 0);
}

DEVINL f32x4 mfma16h(f16x8 a, f16x8 b, f32x4 c) {
  return __builtin_amdgcn_mfma_f32_16x16x32_f16(a, b, c, 0, 0, 0);
}

// ================== 4-phase BK=64 fp16 GEMM core (m201-style) ==================
// C[256x256] = A * B^T, plain fp16 MFMA. 8 waves 4M x 2N, wave-tile 64x128 =
// acc[4][8], BK=64 (2 k-subtiles of 32 per tile).
// LDS: 2 buffers x {A[256 rows][64], B[256][64]} fp16 = 128 KB. Rows are 128 B
// = 8 x 16B slots; slot XOR-swizzled by (row&7) on BOTH the global source of
// the staging load and the ds_read address (rule 21) -> every LDS bank serves
// exactly 8 words per wave read (balanced, conflict-free).
// Per tile t (buf cb=t&1), 4 phases; phase p: {ds_read B j-pair frags (p==0:
// + all 8 A-frags) | stage 1 half-tile | barrier | setprio 16 MFMA setprio |
// barrier}. Stage schedule: ph0/ph1 -> B(t+1) halves into buf cb^1 (dead since
// tile t-1's last read); ph2/ph3 -> A(t+2) halves into buf cb's A-region (all
// A-frags are register-resident after ph0's MFMAs). End-of-tile vmcnt(4)
// leaves exactly A(t+2)'s 4 loads in flight -> counted wait, never 0 (T4),
// with only 2 buffers (m201's half-tile offset pipeline).
// Race safety: every ds_read is consumed by an MFMA inside its own phase, so
// it retires before that phase's closing barrier; each staging write into a
// region is issued >=1 barrier after the last read of that region; per-wave
// vmcnt + barrier makes load-completion visible to all waves.
template <int KSTEPS, int SPLIT_STEP, bool APACKED>
DEVINL void gemm4p_core(const ushort_t* __restrict__ a1, const ushort_t* __restrict__ a2,
                        int lda, const ushort_t* __restrict__ bsrc, int ldb,
                        ushort_t* lds, int tid, f32x4 (&acc)[4][8]) {
  constexpr int BUF = 32768;   // elems per buffer (A 16384 + B 16384)
  constexpr int BOFF = 16384;  // B region offset (elems)
  const int lane = tid & 63, w = tid >> 6;
  const int wr = (w >> 1) * 64, wc = (w & 1) * 128;
  const int slog = (lane & 7) ^ ((lane >> 3) & 7);   // swizzled k-slot (staging)

  // stage half h (128 rows) of A-tile ks into buffer bb (2 gloads/wave)
  auto stA = [&](int bb, int ks, int h) {
    const ushort_t* base = (ks < SPLIT_STEP) ? a1 : a2;
    int kk = APACKED ? (ks & (SPLIT_STEP - 1)) : ks;
#pragma unroll
    for (int g = 0; g < 2; ++g) {
      int row = h * 128 + w * 16 + g * 8;            // wave-uniform
      const ushort_t* s;
      if constexpr (APACKED)   // hi halves of packed hi|lo rows
        s = base + (size_t)(row + (lane >> 3)) * lda +
            (2 * kk + (slog >> 2)) * 64 + (slog & 3) * 8;
      else
        s = base + (size_t)(row + (lane >> 3)) * lda + kk * 64 + slog * 8;
      gload_lds16(s, lds + bb * BUF + row * 64);     // linear dest, lane*16B
    }
  };
  auto stB = [&](int bb, int ks, int h) {
#pragma unroll
    for (int g = 0; g < 2; ++g) {
      int row = h * 128 + w * 16 + g * 8;
      const ushort_t* s = bsrc + (size_t)(row + (lane >> 3)) * ldb + ks * 64 + slog * 8;
      gload_lds16(s, lds + bb * BUF + BOFF + row * 64);
    }
  };
  // frag read: region 0 (A) / BOFF (B), row-base rb, k-subtile ks (0/1)
  auto FR = [&](int bb, int region, int rb, int ks) -> f16x8 {
    int R = rb + (lane & 15);
    int sl = (ks * 4 + (lane >> 4)) ^ (R & 7);
    return *(const f16x8*)(lds + bb * BUF + region + R * 64 + sl * 8);
  };

  // prologue: A(0), B(0), A(1) -> vmcnt(4) leaves A(1) in flight (counted)
  stA(0, 0, 0); stA(0, 0, 1);
  stB(0, 0, 0); stB(0, 0, 1);
  stA(1, 1 & (KSTEPS - 1), 0); stA(1, 1 & (KSTEPS - 1), 1);
  asm volatile("s_waitcnt vmcnt(4)" ::: "memory");
  asm volatile("s_barrier" ::: "memory");

  for (int t = 0; t < KSTEPS; ++t) {
    const int cb = t & 1;
    const int ksB = (t + 1) & (KSTEPS - 1);          // clamped tail: uniform vmcnt
    const int ksA = (t + 2) & (KSTEPS - 1);
    f16x8 rA[4][2];
#pragma unroll
    for (int p = 0; p < 4; ++p) {
      if (p == 0) {
#pragma unroll
        for (int i = 0; i < 4; ++i) {
          rA[i][0] = FR(cb, 0, wr + i * 16, 0);
          rA[i][1] = FR(cb, 0, wr + i * 16, 1);
        }
      }
      f16x8 b00 = FR(cb, BOFF, wc + (2 * p) * 16, 0);
      f16x8 b01 = FR(cb, BOFF, wc + (2 * p) * 16, 1);
      f16x8 b10 = FR(cb, BOFF, wc + (2 * p + 1) * 16, 0);
      f16x8 b11 = FR(cb, BOFF, wc + (2 * p + 1) * 16, 1);
      if (p == 0)      stB(cb ^ 1, ksB, 0);
      else if (p == 1) stB(cb ^ 1, ksB, 1);
      else if (p == 2) stA(cb, ksA, 0);
      else             stA(cb, ksA, 1);
      asm volatile("s_barrier" ::: "memory");
      __builtin_amdgcn_s_setprio(1);
#pragma unroll
      for (int i = 0; i < 4; ++i) {
        acc[i][2 * p]     = mfma16h(rA[i][0], b00, acc[i][2 * p]);
        acc[i][2 * p]     = mfma16h(rA[i][1], b01, acc[i][2 * p]);
        acc[i][2 * p + 1] = mfma16h(rA[i][0], b10, acc[i][2 * p + 1]);
        acc[i][2 * p + 1] = mfma16h(rA[i][1], b11, acc[i][2 * p + 1]);
      }
      __builtin_amdgcn_s_setprio(0);
      if (p == 3) asm volatile("s_waitcnt vmcnt(4)" ::: "memory");
      asm volatile("s_barrier" ::: "memory");
    }
  }
}

// ================== old barrier-light core (scores only, TERMS=2) ==================
template <int KSTEPS, int SPLIT_STEP, int TERMS, int KCHUNK, int NBUF>
DEVINL void gemm_core(const ushort_t* __restrict__ a1, const ushort_t* __restrict__ a2,
                      int lda, const ushort_t* __restrict__ bsrc, int ldb,
                      ushort_t* lds, int tid, f32x4 (&acc)[4][8]) {
  constexpr int BUFE = (TERMS == 2) ? 24576 : 16384;
  constexpr int ALO = 8192;
  constexpr int BOFF = (TERMS == 2) ? 16384 : 8192;
  constexpr int DEPTH = NBUF - 1;
  const int lane = tid & 63, w = tid >> 6;
  const int wr = (w >> 1) * 64, wc = (w & 1) * 128;
  const int scol = (((lane & 3) ^ ((lane >> 3) & 3)) * 8);
  const size_t grow = (size_t)(w * 32 + (lane >> 2));
  const int foff = (lane & 15) * 32 + (((lane >> 4) ^ ((lane >> 1) & 3)) * 8);

  auto stA = [&](int sb, int ks) {
    const ushort_t* base = (ks < SPLIT_STEP) ? a1 : a2;
    int kk = ks & (SPLIT_STEP - 1);
    const ushort_t* s = base + grow * lda + kk * KCHUNK + scol;
    ushort_t* dh = lds + sb * BUFE + w * 1024;
    gload_lds16(s, dh);
    gload_lds16(s + (size_t)16 * lda, dh + 512);
    if constexpr (TERMS == 2) {
      gload_lds16(s + 32, dh + ALO);
      gload_lds16(s + 32 + (size_t)16 * lda, dh + ALO + 512);
    }
  };
  auto stB = [&](int sb, int ks) {
    const ushort_t* s = bsrc + grow * ldb + ks * 32 + scol;
    ushort_t* d = lds + sb * BUFE + BOFF + w * 1024;
    gload_lds16(s, d);
    gload_lds16(s + (size_t)16 * ldb, d + 512);
  };
  auto FR = [&](const ushort_t* rgn, int rb) -> f16x8 {
    return *(const f16x8*)(rgn + rb * 32 + foff);
  };
  auto VMW = [&]() {
    if constexpr (NBUF == 2)       asm volatile("s_waitcnt vmcnt(0)" ::: "memory");
    else if constexpr (TERMS == 2) asm volatile("s_waitcnt vmcnt(6)" ::: "memory");
    else                           asm volatile("s_waitcnt vmcnt(4)" ::: "memory");
  };

#pragma unroll
  for (int d = 0; d < DEPTH; ++d) { stA(d, d); stB(d, d); }
  VMW();
  asm volatile("s_barrier" ::: "memory");

  for (int t = 0; t < KSTEPS; ++t) {
    const int cb = t % NBUF, sb = (t + DEPTH) % NBUF;
    const int ks = (t + DEPTH) & (KSTEPS - 1);
    stA(sb, ks); stB(sb, ks);
    const ushort_t* L = lds + cb * BUFE;
    f16x8 rAh[4], rAl[4], rB[8];
#pragma unroll
    for (int i = 0; i < 4; ++i) rAh[i] = FR(L, wr + i * 16);
#pragma unroll
    for (int j = 0; j < 8; ++j) rB[j] = FR(L + BOFF, wc + j * 16);
    if constexpr (TERMS == 2) {
#pragma unroll
      for (int i = 0; i < 4; ++i) rAl[i] = FR(L + ALO, wr + i * 16);
    }
    __builtin_amdgcn_s_setprio(1);
#pragma unroll
    for (int j = 0; j < 8; ++j)
#pragma unroll
      for (int i = 0; i < 4; ++i) acc[i][j] = mfma16h(rAh[i], rB[j], acc[i][j]);
    if constexpr (TERMS == 2) {
#pragma unroll
      for (int j = 0; j < 8; ++j)
#pragma unroll
        for (int i = 0; i < 4; ++i) acc[i][j] = mfma16h(rAl[i], rB[j], acc[i][j]);
    }
    __builtin_amdgcn_s_setprio(0);
    VMW();
    asm volatile("s_barrier" ::: "memory");
  }
}

// ---------- kernel 1: split t/v/a -> packed fp16 hi|lo + transposed hi ----------
__global__ __launch_bounds__(256) void split_x_kernel(
    const float* __restrict__ v, const float* __restrict__ t, const float* __restrict__ a,
    ushort_t* __restrict__ xpack, ushort_t* __restrict__ xT) {
  __shared__ ushort_t tile[64][65];
  int mod = blockIdx.z;
  const float* src = (mod == 0) ? v : (mod == 1 ? t : a);
  int b = blockIdx.y;
  int s0 = (blockIdx.x >> 4) * 64;
  int f0 = (blockIdx.x & 15) * 64;
  int tid = threadIdx.x;
  ushort_t* xp = xpack + mod * (NX * 2);
  ushort_t* xt = xT + mod * NX;
  int fl = (tid & 15) * 4;
#pragma unroll
  for (int r = 0; r < 4; ++r) {
    int sl = (tid >> 4) + r * 16;
    int row = b * S + s0 + sl;
    float4 x = *(const float4*)(src + (size_t)row * F + f0 + fl);
    ushort_t h0 = f2h(x.x), h1 = f2h(x.y), h2 = f2h(x.z), h3 = f2h(x.w);
    size_t o = pk(row, f0 + fl, XP);
    *(ushort4*)(xp + o) = make_ushort4(h0, h1, h2, h3);
    *(ushort4*)(xp + o + 32) = make_ushort4(
        f2h(x.x - h2f(h0)), f2h(x.y - h2f(h1)),
        f2h(x.z - h2f(h2)), f2h(x.w - h2f(h3)));
    tile[sl][fl] = h0; tile[sl][fl + 1] = h1; tile[sl][fl + 2] = h2; tile[sl][fl + 3] = h3;
  }
  __syncthreads();
#pragma unroll
  for (int r = 0; r < 4; ++r) {
    int flr = (tid >> 4) + r * 16;
    int sl4 = (tid & 15) * 4;
    ushort4 o = make_ushort4(tile[sl4][flr], tile[sl4 + 1][flr],
                             tile[sl4 + 2][flr], tile[sl4 + 3][flr]);
    size_t tidx = ((size_t)(b * F + f0 + flr)) * S + s0 + sl4;
    *(ushort4*)(xt + tidx) = o;
  }
}

// ---------- kernel 2: W (2048x1024) -> WT plain fp16 (1024 rows x K=2048) ----------
__global__ __launch_bounds__(256) void split_w_kernel(
    const float* __restrict__ w0, const float* __restrict__ w1, const float* __restrict__ w2,
    ushort_t* __restrict__ wtpack) {
  __shared__ ushort_t th[64][65];
  int br = blockIdx.z;
  const float* w = (br == 0) ? w0 : (br == 1 ? w1 : w2);
  int g0 = blockIdx.x * 64;
  int f0 = blockIdx.y * 64;
  int tid = threadIdx.x;
  int gl = (tid & 15) * 4;
#pragma unroll
  for (int r = 0; r < 4; ++r) {
    int fl = (tid >> 4) + r * 16;
    float4 x = *(const float4*)(w + (size_t)(f0 + fl) * F + g0 + gl);
    th[fl][gl] = f2h(x.x); th[fl][gl + 1] = f2h(x.y);
    th[fl][gl + 2] = f2h(x.z); th[fl][gl + 3] = f2h(x.w);
  }
  __syncthreads();
  ushort_t* op = wtpack + br * NW;
#pragma unroll
  for (int r = 0; r < 4; ++r) {
    int glr = (tid >> 4) + r * 16;
    int fl4 = (tid & 15) * 4;
    size_t o = (size_t)(g0 + glr) * (2 * F) + f0 + fl4;
    *(ushort4*)(op + o) = make_ushort4(th[fl4][glr], th[fl4 + 1][glr],
                                       th[fl4 + 2][glr], th[fl4 + 3][glr]);
  }
}

// ---------- kernel 3: Feat = tanh(concat(x1,x2) @ W + b), fp16 out ----------
// 4-phase BK=64 core, 128 KB LDS, A = packed-hi (plain fp16 accuracy).
__global__ __launch_bounds__(512, 2) void feat_gemm_kernel(
    const ushort_t* __restrict__ xpack, const ushort_t* __restrict__ wtpack,
    const float* __restrict__ b0, const float* __restrict__ b1, const float* __restrict__ b2,
    ushort_t* __restrict__ fpack) {
  constexpr int M1[3] = {1, 1, 2};   // t, t, a
  constexpr int M2[3] = {0, 2, 0};   // v, a, v
  __shared__ __attribute__((aligned(16))) ushort_t lds[2 * 32768];   // 128 KB
  int br = blockIdx.z;
  int lin = blockIdx.x;              // 0..127
  int gm0 = ((lin & 7) * 4 + ((lin >> 3) & 3)) * 256;
  int gn0 = (lin >> 5) * 256;
  int tid = threadIdx.x, lane = tid & 63, w = tid >> 6;
  const ushort_t* a1 = xpack + M1[br] * (NX * 2) + (size_t)gm0 * XP;
  const ushort_t* a2 = xpack + M2[br] * (NX * 2) + (size_t)gm0 * XP;
  const ushort_t* bb = wtpack + br * NW + (size_t)gn0 * (2 * F);
  f32x4 acc[4][8] = {};
  gemm4p_core<32, 16, true>(a1, a2, XP, bb, 2 * F, lds, tid, acc);
  const float* bias = (br == 0) ? b0 : (br == 1 ? b1 : b2);
  ushort_t* op = fpack + br * NX;
  int wr = (w >> 1) * 64, wc = (w & 1) * 128;
#pragma unroll
  for (int i = 0; i < 4; ++i)
#pragma unroll
    for (int j = 0; j < 8; ++j)
#pragma unroll
      for (int r = 0; r < 4; ++r) {
        int row = gm0 + wr + i * 16 + (lane >> 4) * 4 + r;
        int col = gn0 + wc + j * 16 + (lane & 15);
        op[(size_t)row * F + col] = f2h(tanhf(acc[i][j][r] + bias[col]));
      }
}

// ---------- kernel 4: scores = q @ feat^T, fp32 out (q kept 2-term split) ----------
__global__ __launch_bounds__(512, 2) void scores_gemm_kernel(
    const ushort_t* __restrict__ xpack, const ushort_t* __restrict__ fpack,
    float* __restrict__ scores) {
  constexpr int QM[3] = {2, 0, 1};   // a, v, t
  __shared__ __attribute__((aligned(16))) ushort_t lds[3 * 24576];   // 144 KB
  int z = blockIdx.z;
  int br = z >> 4, b = z & 15;
  int gm0 = blockIdx.x * 256;
  int gn0 = blockIdx.y * 256;
  int tid = threadIdx.x, lane = tid & 63, w = tid >> 6;
  const ushort_t* a1 = xpack + QM[br] * (NX * 2) + (size_t)(b * S + gm0) * XP;
  const ushort_t* bb = fpack + br * NX + (size_t)(b * S + gn0) * F;
  f32x4 acc[4][8] = {};
  gemm_core<32, 32, 2, 64, 3>(a1, a1, XP, bb, F, lds, tid, acc);
  float* out = scores + (size_t)z * S * S;
  int wr = (w >> 1) * 64, wc = (w & 1) * 128;
#pragma unroll
  for (int i = 0; i < 4; ++i)
#pragma unroll
    for (int j = 0; j < 8; ++j)
#pragma unroll
      for (int r = 0; r < 4; ++r) {
        int row = gm0 + wr + i * 16 + (lane >> 4) * 4 + r;
        int col = gn0 + wc + j * 16 + (lane & 15);
        out[(size_t)row * S + col] = acc[i][j][r];
      }
}

// ---------- kernel 5: row softmax (512), fp32 in -> fp16 p ----------
__global__ __launch_bounds__(256) void softmax_kernel(
    const float* __restrict__ scores, ushort_t* __restrict__ p) {
  int wave = threadIdx.x >> 6, lane = threadIdx.x & 63;
  int row = blockIdx.x * 4 + wave;
  const float* src = scores + (size_t)row * S;
  float4 v0 = *(const float4*)(src + lane * 8);
  float4 v1 = *(const float4*)(src + lane * 8 + 4);
  float m = fmaxf(fmaxf(fmaxf(v0.x, v0.y), fmaxf(v0.z, v0.w)),
                  fmaxf(fmaxf(v1.x, v1.y), fmaxf(v1.z, v1.w)));
#pragma unroll
  for (int d = 1; d < 64; d <<= 1) m = fmaxf(m, __shfl_xor(m, d));
  float e[8] = {expf(v0.x - m), expf(v0.y - m), expf(v0.z - m), expf(v0.w - m),
                expf(v1.x - m), expf(v1.y - m), expf(v1.z - m), expf(v1.w - m)};
  float s = ((e[0] + e[1]) + (e[2] + e[3])) + ((e[4] + e[5]) + (e[6] + e[7]));
#pragma unroll
  for (int d = 1; d < 64; d <<= 1) s += __shfl_xor(s, d);
  float inv = 1.0f / s;
  u16x8 o;
#pragma unroll
  for (int j = 0; j < 8; ++j) o[j] = f2h(e[j] * inv);
  *(u16x8*)(p + (size_t)row * S + lane * 8) = o;
}

// ---------- kernel 6: O = (p @ q) * feat, fp32 out ----------
// 4-phase BK=64 core, plain fp16 A/B.
__global__ __launch_bounds__(512, 2) void pv_gemm_kernel(
    const ushort_t* __restrict__ p, const ushort_t* __restrict__ xT,
    const ushort_t* __restrict__ fpack, float* __restrict__ out) {
  constexpr int QM[3] = {2, 0, 1};
  __shared__ __attribute__((aligned(16))) ushort_t lds[2 * 32768];   // 128 KB
  int z = blockIdx.z;
  int br = z >> 4, b = z & 15;
  int gm0 = blockIdx.x * 256;
  int gn0 = blockIdx.y * 256;
  int tid = threadIdx.x, lane = tid & 63, w = tid >> 6;
  const ushort_t* pa = p + (size_t)z * S * S + (size_t)gm0 * S;
  const ushort_t* qt = xT + QM[br] * NX + (size_t)b * F * S + (size_t)gn0 * S;  // [f][s]
  f32x4 acc[4][8] = {};
  gemm4p_core<8, 8, false>(pa, pa, S, qt, S, lds, tid, acc);
  const ushort_t* fp = fpack + br * NX;
  int wr = (w >> 1) * 64, wc = (w & 1) * 128;
#pragma unroll
  for (int i = 0; i < 4; ++i)
#pragma unroll
    for (int j = 0; j < 8; ++j)
#pragma unroll
      for (int r = 0; r < 4; ++r) {
        int row = gm0 + wr + i * 16 + (lane >> 4) * 4 + r;
        int col = gn0 + wc + j * 16 + (lane & 15);
        float fe = h2f(fp[(size_t)(b * S + row) * F + col]);
        out[(size_t)(b * S + row) * (3 * F) + br * F + col] = acc[i][j][r] * fe;
      }
}

extern "C" void kernel_launch(void* const* d_in, const int* in_sizes, int n_in,
                              void* d_out, int out_size, void* d_ws, size_t ws_size,
                              hipStream_t stream) {
  (void)in_sizes; (void)n_in; (void)out_size; (void)ws_size;
  const float* v = (const float*)d_in[0];
  const float* t = (const float*)d_in[1];
  const float* a = (const float*)d_in[2];
  const float* W_tv = (const float*)d_in[3];
  const float* b_tv = (const float*)d_in[4];
  const float* W_ta = (const float*)d_in[5];
  const float* b_ta = (const float*)d_in[6];
  const float* W_av = (const float*)d_in[7];
  const float* b_av = (const float*)d_in[8];
  float* out = (float*)d_out;

  // ws layout (~290 MB total)
  ushort_t* xpack = (ushort_t*)d_ws;            // 3 * NX*2 (fp16 hi|lo packed)
  ushort_t* xT = xpack + 3 * (NX * 2);          // 3 * NX (fp16 plain, [f][s])
  ushort_t* wtpack = xT + 3 * NX;               // 3 * NW (fp16 plain)
  ushort_t* fpack = wtpack + 3 * NW;            // 3 * NX (fp16 plain)
  float* scores = (float*)(fpack + 3 * NX);
  ushort_t* pbuf = (ushort_t*)(scores + NSC);

  split_x_kernel<<<dim3(128, 16, 3), 256, 0, stream>>>(v, t, a, xpack, xT);
  split_w_kernel<<<dim3(16, 32, 3), 256, 0, stream>>>(W_tv, W_ta, W_av, wtpack);
  feat_gemm_kernel<<<dim3(128, 1, 3), 512, 0, stream>>>(xpack, wtpack,
                                                        b_tv, b_ta, b_av, fpack);
  scores_gemm_kernel<<<dim3(2, 2, 48), 512, 0, stream>>>(xpack, fpack, scores);
  softmax_kernel<<<dim3((3 * B * S) / 4), 256, 0, stream>>>(scores, pbuf);
  pv_gemm_kernel<<<dim3(2, 4, 48), 512, 0, stream>>>(pbuf, xT, fpack, out);
}

// Round 11
// 333.621 us; speedup vs baseline: 5.0716x; 1.0115x over previous
//
#include <hip/hip_runtime.h>

typedef unsigned short ushort_t;
typedef _Float16 f16x8 __attribute__((ext_vector_type(8)));
typedef float f32x4 __attribute__((ext_vector_type(4)));
typedef unsigned short u16x8 __attribute__((ext_vector_type(8)));

#define DEVINL __device__ __forceinline__

constexpr int B = 16, S = 512, F = 1024;
constexpr int M_ROWS = B * S;                    // 8192
constexpr size_t NX = (size_t)M_ROWS * F;        // 8,388,608 elems per modality
constexpr size_t NW = (size_t)F * (2 * F);       // 2,097,152 elems per branch
constexpr size_t NSC = (size_t)3 * B * S * S;    // 12,582,912 score elems

// packed pitch for split-x: per row, chunk c holds 32 hi at c*64, 32 lo at c*64+32
constexpr int XP = 2 * F;        // 2048

// ---------- fp16 helpers ----------
DEVINL ushort_t f2h(float f) { return __builtin_bit_cast(ushort_t, (_Float16)f); }
DEVINL float h2f(ushort_t h) { return (float)__builtin_bit_cast(_Float16, h); }
DEVINL size_t pk(int row, int k, int pitch) {
  return (size_t)row * pitch + ((k >> 5) * 64) + (k & 31);
}

// ---------- async global->LDS (16B per lane) ----------
DEVINL void gload_lds16(const void* g, void* l) {
  __builtin_amdgcn_global_load_lds(
      (__attribute__((address_space(1))) void*)(g),
      (__attribute__((address_space(3))) void*)(l), 16, 0, 0);
}

DEVINL f32x4 mfma16h(f16x8 a, f16x8 b, f32x4 c) {
  return __builtin_amdgcn_mfma_f32_16x16x32_f16(a, b, c, 0, 0, 0);
}

// ================== 4-phase BK=64 fp16 GEMM core, VALU-hoisted ==================
// Same schedule/sync skeleton as R10 (proven correct): 2 buffers x {A[256][64],
// B[256][64]} = 128 KB, 4 phases/tile, counted vmcnt(4) at tile end (never 0),
// stage B(t+1)->buf^1 at ph0/ph1, A(t+2)->buf A-region at ph2/ph3.
// New in R11:
//  (a) tile loop unrolled x2 -> buffer index is a literal; all ds_read
//      addresses become thread-base + compile-time immediate (zero VALU/read);
//      swizzle terms hoisted ((ks*4+lane>>4)^(lane&7) is loop-invariant).
//  (b) B-frag reads pipelined one phase ahead: MFMA(p) consumes frags read at
//      p-1 (a barrier ago), so compiler's counted lgkmcnt leaves the fresh
//      reads outstanding instead of stalling. Hazard-free: buffer cb's B
//      region has no writes during tile t; A-writes (ph2/3) follow all
//      A-reads (ph0); cross-tile reads gated by vmcnt(4)+barrier as before.
// Accumulation order per acc element identical to R10 (bit-identical output).
template <int KSTEPS, int SPLIT_STEP, bool APACKED>
DEVINL void gemm4p_core(const ushort_t* __restrict__ a1, const ushort_t* __restrict__ a2,
                        int lda, const ushort_t* __restrict__ bsrc, int ldb,
                        ushort_t* lds, int tid, f32x4 (&acc)[4][8]) {
  constexpr int BUF = 32768;   // elems per buffer (A 16384 + B 16384)
  constexpr int BOFF = 16384;  // B region offset (elems)
  constexpr int KM = KSTEPS - 1;
  constexpr int AKC = APACKED ? 128 : 64;   // A row elems per k-tile
  const int lane = tid & 63, w = tid >> 6;
  const int wr = (w >> 1) * 64, wc = (w & 1) * 128;
  const int slog = (lane & 7) ^ ((lane >> 3) & 7);   // swizzled k-slot (staging)

  // ---- hoisted per-thread ds_read bases (row + swizzled slot, ks=0/1) ----
  const int sl0 = ((lane >> 4) ^ (lane & 7)) * 8;          // ks=0 slot bytes/2
  const int sl1 = ((4 + (lane >> 4)) ^ (lane & 7)) * 8;    // ks=1
  const ushort_t* dsA0 = lds + (wr + (lane & 15)) * 64 + sl0;
  const ushort_t* dsA1 = lds + (wr + (lane & 15)) * 64 + sl1;
  const ushort_t* dsB0 = lds + BOFF + (wc + (lane & 15)) * 64 + sl0;
  const ushort_t* dsB1 = lds + BOFF + (wc + (lane & 15)) * 64 + sl1;

  // ---- hoisted per-thread gload bases ----
  const size_t ldaS = (size_t)lda, ldbS = (size_t)ldb;
  const int colA = APACKED ? ((slog >> 2) * 64 + (slog & 3) * 8) : slog * 8;
  const ushort_t* gA1 = a1 + (size_t)(w * 16 + (lane >> 3)) * ldaS + colA;
  const ushort_t* gA2 = a2 + (size_t)(w * 16 + (lane >> 3)) * ldaS + colA;
  const ushort_t* gB  = bsrc + (size_t)(w * 16 + (lane >> 3)) * ldbS + slog * 8;
  ushort_t* dA = lds + (w * 16) * 64;          // + bb*BUF + h*8192, lane adds 16B
  ushort_t* dB = lds + BOFF + (w * 16) * 64;

  auto stA = [&](int bb, int ks, int h) {
    const ushort_t* base = ((SPLIT_STEP >= KSTEPS) || (ks < SPLIT_STEP)) ? gA1 : gA2;
    const ushort_t* s = base + (ks & (SPLIT_STEP - 1)) * AKC + (size_t)(h * 128) * ldaS;
    ushort_t* d = dA + bb * BUF + h * 8192;
    gload_lds16(s, d);
    gload_lds16(s + 8 * ldaS, d + 512);
  };
  auto stB = [&](int bb, int ks, int h) {
    const ushort_t* s = gB + ks * 64 + (size_t)(h * 128) * ldbS;
    ushort_t* d = dB + bb * BUF + h * 8192;
    gload_lds16(s, d);
    gload_lds16(s + 8 * ldbS, d + 512);
  };

#define BAR asm volatile("s_barrier" ::: "memory")
#define RDB(J)                                              \
  Bn0 = *(const f16x8*)(rB0 + (J) * 1024);                  \
  Bn1 = *(const f16x8*)(rB1 + (J) * 1024);                  \
  Bn2 = *(const f16x8*)(rB0 + ((J) + 1) * 1024);            \
  Bn3 = *(const f16x8*)(rB1 + ((J) + 1) * 1024);
#define PHASE_MM(JP)                                        \
  __builtin_amdgcn_s_setprio(1);                            \
  _Pragma("unroll")                                         \
  for (int i = 0; i < 4; ++i) {                             \
    acc[i][2 * (JP)]     = mfma16h(rA[i][0], Bc0, acc[i][2 * (JP)]);     \
    acc[i][2 * (JP)]     = mfma16h(rA[i][1], Bc1, acc[i][2 * (JP)]);     \
    acc[i][2 * (JP) + 1] = mfma16h(rA[i][0], Bc2, acc[i][2 * (JP) + 1]); \
    acc[i][2 * (JP) + 1] = mfma16h(rA[i][1], Bc3, acc[i][2 * (JP) + 1]); \
  }                                                         \
  __builtin_amdgcn_s_setprio(0);
#define SWAPB  Bc0 = Bn0; Bc1 = Bn1; Bc2 = Bn2; Bc3 = Bn3;
#define TILE(BB, T) {                                       \
  const int ksB = ((T) + 1) & KM;                           \
  const int ksA = ((T) + 2) & KM;                           \
  const ushort_t* rA0 = dsA0 + (BB) * BUF;                  \
  const ushort_t* rA1 = dsA1 + (BB) * BUF;                  \
  const ushort_t* rB0 = dsB0 + (BB) * BUF;                  \
  const ushort_t* rB1 = dsB1 + (BB) * BUF;                  \
  f16x8 rA[4][2];                                           \
  f16x8 Bc0, Bc1, Bc2, Bc3, Bn0, Bn1, Bn2, Bn3;             \
  _Pragma("unroll")                                         \
  for (int i = 0; i < 4; ++i) {                             \
    rA[i][0] = *(const f16x8*)(rA0 + i * 1024);             \
    rA[i][1] = *(const f16x8*)(rA1 + i * 1024);             \
  }                                                         \
  Bc0 = *(const f16x8*)(rB0);                               \
  Bc1 = *(const f16x8*)(rB1);                               \
  Bc2 = *(const f16x8*)(rB0 + 1024);                        \
  Bc3 = *(const f16x8*)(rB1 + 1024);                        \
  RDB(2)                                                    \
  stB(BB ^ 1, ksB, 0);                                      \
  BAR; PHASE_MM(0) BAR;                                     \
  SWAPB RDB(4)                                              \
  stB(BB ^ 1, ksB, 1);                                      \
  BAR; PHASE_MM(1) BAR;                                     \
  SWAPB RDB(6)                                              \
  stA(BB, ksA, 0);                                          \
  BAR; PHASE_MM(2) BAR;                                     \
  SWAPB                                                     \
  stA(BB, ksA, 1);                                          \
  BAR; PHASE_MM(3)                                          \
  asm volatile("s_waitcnt vmcnt(4)" ::: "memory");          \
  BAR;                                                      \
}

  // prologue: A(0), B(0), A(1) -> vmcnt(4) leaves A(1) in flight (counted)
  stA(0, 0, 0); stA(0, 0, 1);
  stB(0, 0, 0); stB(0, 0, 1);
  stA(1, 1 & KM, 0); stA(1, 1 & KM, 1);
  asm volatile("s_waitcnt vmcnt(4)" ::: "memory");
  BAR;

  for (int t = 0; t < KSTEPS; t += 2) {
    TILE(0, t)
    TILE(1, t + 1)
  }
#undef TILE
#undef SWAPB
#undef PHASE_MM
#undef RDB
#undef BAR
}

// ================== old barrier-light core (scores only, TERMS=2) ==================
template <int KSTEPS, int SPLIT_STEP, int TERMS, int KCHUNK, int NBUF>
DEVINL void gemm_core(const ushort_t* __restrict__ a1, const ushort_t* __restrict__ a2,
                      int lda, const ushort_t* __restrict__ bsrc, int ldb,
                      ushort_t* lds, int tid, f32x4 (&acc)[4][8]) {
  constexpr int BUFE = (TERMS == 2) ? 24576 : 16384;
  constexpr int ALO = 8192;
  constexpr int BOFF = (TERMS == 2) ? 16384 : 8192;
  constexpr int DEPTH = NBUF - 1;
  const int lane = tid & 63, w = tid >> 6;
  const int wr = (w >> 1) * 64, wc = (w & 1) * 128;
  const int scol = (((lane & 3) ^ ((lane >> 3) & 3)) * 8);
  const size_t grow = (size_t)(w * 32 + (lane >> 2));
  const int foff = (lane & 15) * 32 + (((lane >> 4) ^ ((lane >> 1) & 3)) * 8);

  auto stA = [&](int sb, int ks) {
    const ushort_t* base = (ks < SPLIT_STEP) ? a1 : a2;
    int kk = ks & (SPLIT_STEP - 1);
    const ushort_t* s = base + grow * lda + kk * KCHUNK + scol;
    ushort_t* dh = lds + sb * BUFE + w * 1024;
    gload_lds16(s, dh);
    gload_lds16(s + (size_t)16 * lda, dh + 512);
    if constexpr (TERMS == 2) {
      gload_lds16(s + 32, dh + ALO);
      gload_lds16(s + 32 + (size_t)16 * lda, dh + ALO + 512);
    }
  };
  auto stB = [&](int sb, int ks) {
    const ushort_t* s = bsrc + grow * ldb + ks * 32 + scol;
    ushort_t* d = lds + sb * BUFE + BOFF + w * 1024;
    gload_lds16(s, d);
    gload_lds16(s + (size_t)16 * ldb, d + 512);
  };
  auto FR = [&](const ushort_t* rgn, int rb) -> f16x8 {
    return *(const f16x8*)(rgn + rb * 32 + foff);
  };
  auto VMW = [&]() {
    if constexpr (NBUF == 2)       asm volatile("s_waitcnt vmcnt(0)" ::: "memory");
    else if constexpr (TERMS == 2) asm volatile("s_waitcnt vmcnt(6)" ::: "memory");
    else                           asm volatile("s_waitcnt vmcnt(4)" ::: "memory");
  };

#pragma unroll
  for (int d = 0; d < DEPTH; ++d) { stA(d, d); stB(d, d); }
  VMW();
  asm volatile("s_barrier" ::: "memory");

  for (int t = 0; t < KSTEPS; ++t) {
    const int cb = t % NBUF, sb = (t + DEPTH) % NBUF;
    const int ks = (t + DEPTH) & (KSTEPS - 1);
    stA(sb, ks); stB(sb, ks);
    const ushort_t* L = lds + cb * BUFE;
    f16x8 rAh[4], rAl[4], rB[8];
#pragma unroll
    for (int i = 0; i < 4; ++i) rAh[i] = FR(L, wr + i * 16);
#pragma unroll
    for (int j = 0; j < 8; ++j) rB[j] = FR(L + BOFF, wc + j * 16);
    if constexpr (TERMS == 2) {
#pragma unroll
      for (int i = 0; i < 4; ++i) rAl[i] = FR(L + ALO, wr + i * 16);
    }
    __builtin_amdgcn_s_setprio(1);
#pragma unroll
    for (int j = 0; j < 8; ++j)
#pragma unroll
      for (int i = 0; i < 4; ++i) acc[i][j] = mfma16h(rAh[i], rB[j], acc[i][j]);
    if constexpr (TERMS == 2) {
#pragma unroll
      for (int j = 0; j < 8; ++j)
#pragma unroll
        for (int i = 0; i < 4; ++i) acc[i][j] = mfma16h(rAl[i], rB[j], acc[i][j]);
    }
    __builtin_amdgcn_s_setprio(0);
    VMW();
    asm volatile("s_barrier" ::: "memory");
  }
}

// ---------- kernel 1: split t/v/a -> packed fp16 hi|lo + transposed hi ----------
__global__ __launch_bounds__(256) void split_x_kernel(
    const float* __restrict__ v, const float* __restrict__ t, const float* __restrict__ a,
    ushort_t* __restrict__ xpack, ushort_t* __restrict__ xT) {
  __shared__ ushort_t tile[64][65];
  int mod = blockIdx.z;
  const float* src = (mod == 0) ? v : (mod == 1 ? t : a);
  int b = blockIdx.y;
  int s0 = (blockIdx.x >> 4) * 64;
  int f0 = (blockIdx.x & 15) * 64;
  int tid = threadIdx.x;
  ushort_t* xp = xpack + mod * (NX * 2);
  ushort_t* xt = xT + mod * NX;
  int fl = (tid & 15) * 4;
#pragma unroll
  for (int r = 0; r < 4; ++r) {
    int sl = (tid >> 4) + r * 16;
    int row = b * S + s0 + sl;
    float4 x = *(const float4*)(src + (size_t)row * F + f0 + fl);
    ushort_t h0 = f2h(x.x), h1 = f2h(x.y), h2 = f2h(x.z), h3 = f2h(x.w);
    size_t o = pk(row, f0 + fl, XP);
    *(ushort4*)(xp + o) = make_ushort4(h0, h1, h2, h3);
    *(ushort4*)(xp + o + 32) = make_ushort4(
        f2h(x.x - h2f(h0)), f2h(x.y - h2f(h1)),
        f2h(x.z - h2f(h2)), f2h(x.w - h2f(h3)));
    tile[sl][fl] = h0; tile[sl][fl + 1] = h1; tile[sl][fl + 2] = h2; tile[sl][fl + 3] = h3;
  }
  __syncthreads();
#pragma unroll
  for (int r = 0; r < 4; ++r) {
    int flr = (tid >> 4) + r * 16;
    int sl4 = (tid & 15) * 4;
    ushort4 o = make_ushort4(tile[sl4][flr], tile[sl4 + 1][flr],
                             tile[sl4 + 2][flr], tile[sl4 + 3][flr]);
    size_t tidx = ((size_t)(b * F + f0 + flr)) * S + s0 + sl4;
    *(ushort4*)(xt + tidx) = o;
  }
}

// ---------- kernel 2: W (2048x1024) -> WT plain fp16 (1024 rows x K=2048) ----------
__global__ __launch_bounds__(256) void split_w_kernel(
    const float* __restrict__ w0, const float* __restrict__ w1, const float* __restrict__ w2,
    ushort_t* __restrict__ wtpack) {
  __shared__ ushort_t th[64][65];
  int br = blockIdx.z;
  const float* w = (br == 0) ? w0 : (br == 1 ? w1 : w2);
  int g0 = blockIdx.x * 64;
  int f0 = blockIdx.y * 64;
  int tid = threadIdx.x;
  int gl = (tid & 15) * 4;
#pragma unroll
  for (int r = 0; r < 4; ++r) {
    int fl = (tid >> 4) + r * 16;
    float4 x = *(const float4*)(w + (size_t)(f0 + fl) * F + g0 + gl);
    th[fl][gl] = f2h(x.x); th[fl][gl + 1] = f2h(x.y);
    th[fl][gl + 2] = f2h(x.z); th[fl][gl + 3] = f2h(x.w);
  }
  __syncthreads();
  ushort_t* op = wtpack + br * NW;
#pragma unroll
  for (int r = 0; r < 4; ++r) {
    int glr = (tid >> 4) + r * 16;
    int fl4 = (tid & 15) * 4;
    size_t o = (size_t)(g0 + glr) * (2 * F) + f0 + fl4;
    *(ushort4*)(op + o) = make_ushort4(th[fl4][glr], th[fl4 + 1][glr],
                                       th[fl4 + 2][glr], th[fl4 + 3][glr]);
  }
}

// ---------- kernel 3: Feat = tanh(concat(x1,x2) @ W + b), fp16 out ----------
__global__ __launch_bounds__(512, 2) void feat_gemm_kernel(
    const ushort_t* __restrict__ xpack, const ushort_t* __restrict__ wtpack,
    const float* __restrict__ b0, const float* __restrict__ b1, const float* __restrict__ b2,
    ushort_t* __restrict__ fpack) {
  constexpr int M1[3] = {1, 1, 2};   // t, t, a
  constexpr int M2[3] = {0, 2, 0};   // v, a, v
  __shared__ __attribute__((aligned(16))) ushort_t lds[2 * 32768];   // 128 KB
  int br = blockIdx.z;
  int lin = blockIdx.x;              // 0..127
  int gm0 = ((lin & 7) * 4 + ((lin >> 3) & 3)) * 256;
  int gn0 = (lin >> 5) * 256;
  int tid = threadIdx.x, lane = tid & 63, w = tid >> 6;
  const ushort_t* a1 = xpack + M1[br] * (NX * 2) + (size_t)gm0 * XP;
  const ushort_t* a2 = xpack + M2[br] * (NX * 2) + (size_t)gm0 * XP;
  const ushort_t* bb = wtpack + br * NW + (size_t)gn0 * (2 * F);
  f32x4 acc[4][8] = {};
  gemm4p_core<32, 16, true>(a1, a2, XP, bb, 2 * F, lds, tid, acc);
  const float* bias = (br == 0) ? b0 : (br == 1 ? b1 : b2);
  ushort_t* op = fpack + br * NX;
  int wr = (w >> 1) * 64, wc = (w & 1) * 128;
#pragma unroll
  for (int i = 0; i < 4; ++i)
#pragma unroll
    for (int j = 0; j < 8; ++j)
#pragma unroll
      for (int r = 0; r < 4; ++r) {
        int row = gm0 + wr + i * 16 + (lane >> 4) * 4 + r;
        int col = gn0 + wc + j * 16 + (lane & 15);
        op[(size_t)row * F + col] = f2h(tanhf(acc[i][j][r] + bias[col]));
      }
}

// ---------- kernel 4: scores = q @ feat^T, fp32 out (q kept 2-term split) ----------
__global__ __launch_bounds__(512, 2) void scores_gemm_kernel(
    const ushort_t* __restrict__ xpack, const ushort_t* __restrict__ fpack,
    float* __restrict__ scores) {
  constexpr int QM[3] = {2, 0, 1};   // a, v, t
  __shared__ __attribute__((aligned(16))) ushort_t lds[3 * 24576];   // 144 KB
  int z = blockIdx.z;
  int br = z >> 4, b = z & 15;
  int gm0 = blockIdx.x * 256;
  int gn0 = blockIdx.y * 256;
  int tid = threadIdx.x, lane = tid & 63, w = tid >> 6;
  const ushort_t* a1 = xpack + QM[br] * (NX * 2) + (size_t)(b * S + gm0) * XP;
  const ushort_t* bb = fpack + br * NX + (size_t)(b * S + gn0) * F;
  f32x4 acc[4][8] = {};
  gemm_core<32, 32, 2, 64, 3>(a1, a1, XP, bb, F, lds, tid, acc);
  float* out = scores + (size_t)z * S * S;
  int wr = (w >> 1) * 64, wc = (w & 1) * 128;
#pragma unroll
  for (int i = 0; i < 4; ++i)
#pragma unroll
    for (int j = 0; j < 8; ++j)
#pragma unroll
      for (int r = 0; r < 4; ++r) {
        int row = gm0 + wr + i * 16 + (lane >> 4) * 4 + r;
        int col = gn0 + wc + j * 16 + (lane & 15);
        out[(size_t)row * S + col] = acc[i][j][r];
      }
}

// ---------- kernel 5: row softmax (512), fp32 in -> fp16 p ----------
__global__ __launch_bounds__(256) void softmax_kernel(
    const float* __restrict__ scores, ushort_t* __restrict__ p) {
  int wave = threadIdx.x >> 6, lane = threadIdx.x & 63;
  int row = blockIdx.x * 4 + wave;
  const float* src = scores + (size_t)row * S;
  float4 v0 = *(const float4*)(src + lane * 8);
  float4 v1 = *(const float4*)(src + lane * 8 + 4);
  float m = fmaxf(fmaxf(fmaxf(v0.x, v0.y), fmaxf(v0.z, v0.w)),
                  fmaxf(fmaxf(v1.x, v1.y), fmaxf(v1.z, v1.w)));
#pragma unroll
  for (int d = 1; d < 64; d <<= 1) m = fmaxf(m, __shfl_xor(m, d));
  float e[8] = {expf(v0.x - m), expf(v0.y - m), expf(v0.z - m), expf(v0.w - m),
                expf(v1.x - m), expf(v1.y - m), expf(v1.z - m), expf(v1.w - m)};
  float s = ((e[0] + e[1]) + (e[2] + e[3])) + ((e[4] + e[5]) + (e[6] + e[7]));
#pragma unroll
  for (int d = 1; d < 64; d <<= 1) s += __shfl_xor(s, d);
  float inv = 1.0f / s;
  u16x8 o;
#pragma unroll
  for (int j = 0; j < 8; ++j) o[j] = f2h(e[j] * inv);
  *(u16x8*)(p + (size_t)row * S + lane * 8) = o;
}

// ---------- kernel 6: O = (p @ q) * feat, fp32 out ----------
__global__ __launch_bounds__(512, 2) void pv_gemm_kernel(
    const ushort_t* __restrict__ p, const ushort_t* __restrict__ xT,
    const ushort_t* __restrict__ fpack, float* __restrict__ out) {
  constexpr int QM[3] = {2, 0, 1};
  __shared__ __attribute__((aligned(16))) ushort_t lds[2 * 32768];   // 128 KB
  int z = blockIdx.z;
  int br = z >> 4, b = z & 15;
  int gm0 = blockIdx.x * 256;
  int gn0 = blockIdx.y * 256;
  int tid = threadIdx.x, lane = tid & 63, w = tid >> 6;
  const ushort_t* pa = p + (size_t)z * S * S + (size_t)gm0 * S;
  const ushort_t* qt = xT + QM[br] * NX + (size_t)b * F * S + (size_t)gn0 * S;  // [f][s]
  f32x4 acc[4][8] = {};
  gemm4p_core<8, 8, false>(pa, pa, S, qt, S, lds, tid, acc);
  const ushort_t* fp = fpack + br * NX;
  int wr = (w >> 1) * 64, wc = (w & 1) * 128;
#pragma unroll
  for (int i = 0; i < 4; ++i)
#pragma unroll
    for (int j = 0; j < 8; ++j)
#pragma unroll
      for (int r = 0; r < 4; ++r) {
        int row = gm0 + wr + i * 16 + (lane >> 4) * 4 + r;
        int col = gn0 + wc + j * 16 + (lane & 15);
        float fe = h2f(fp[(size_t)(b * S + row) * F + col]);
        out[(size_t)(b * S + row) * (3 * F) + br * F + col] = acc[i][j][r] * fe;
      }
}

extern "C" void kernel_launch(void* const* d_in, const int* in_sizes, int n_in,
                              void* d_out, int out_size, void* d_ws, size_t ws_size,
                              hipStream_t stream) {
  (void)in_sizes; (void)n_in; (void)out_size; (void)ws_size;
  const float* v = (const float*)d_in[0];
  const float* t = (const float*)d_in[1];
  const float* a = (const float*)d_in[2];
  const float* W_tv = (const float*)d_in[3];
  const float* b_tv = (const float*)d_in[4];
  const float* W_ta = (const float*)d_in[5];
  const float* b_ta = (const float*)d_in[6];
  const float* W_av = (const float*)d_in[7];
  const float* b_av = (const float*)d_in[8];
  float* out = (float*)d_out;

  // ws layout (~290 MB total)
  ushort_t* xpack = (ushort_t*)d_ws;            // 3 * NX*2 (fp16 hi|lo packed)
  ushort_t* xT = xpack + 3 * (NX * 2);          // 3 * NX (fp16 plain, [f][s])
  ushort_t* wtpack = xT + 3 * NX;               // 3 * NW (fp16 plain)
  ushort_t* fpack = wtpack + 3 * NW;            // 3 * NX (fp16 plain)
  float* scores = (float*)(fpack + 3 * NX);
  ushort_t* pbuf = (ushort_t*)(scores + NSC);

  split_x_kernel<<<dim3(128, 16, 3), 256, 0, stream>>>(v, t, a, xpack, xT);
  split_w_kernel<<<dim3(16, 32, 3), 256, 0, stream>>>(W_tv, W_ta, W_av, wtpack);
  feat_gemm_kernel<<<dim3(128, 1, 3), 512, 0, stream>>>(xpack, wtpack,
                                                        b_tv, b_ta, b_av, fpack);
  scores_gemm_kernel<<<dim3(2, 2, 48), 512, 0, stream>>>(xpack, fpack, scores);
  softmax_kernel<<<dim3((3 * B * S) / 4), 256, 0, stream>>>(scores, pbuf);
  pv_gemm_kernel<<<dim3(2, 4, 48), 512, 0, stream>>>(pbuf, xT, fpack, out);
}

// Round 12
// 295.207 us; speedup vs baseline: 5.7316x; 1.1301x over previous
//
#include <hip/hip_runtime.h>

typedef unsigned short ushort_t;
typedef _Float16 f16x8 __attribute__((ext_vector_type(8)));
typedef float f32x4 __attribute__((ext_vector_type(4)));
typedef unsigned short u16x8 __attribute__((ext_vector_type(8)));

#define DEVINL __device__ __forceinline__

constexpr int B = 16, S = 512, F = 1024;
constexpr int M_ROWS = B * S;                    // 8192
constexpr size_t NX = (size_t)M_ROWS * F;        // 8,388,608 elems per modality
constexpr size_t NW = (size_t)F * (2 * F);       // 2,097,152 elems per branch
constexpr size_t NSC = (size_t)3 * B * S * S;    // 12,582,912 score elems

// ---------- fp16 helpers ----------
DEVINL ushort_t f2h(float f) { return __builtin_bit_cast(ushort_t, (_Float16)f); }
DEVINL float h2f(ushort_t h) { return (float)__builtin_bit_cast(_Float16, h); }

// ---------- async global->LDS (16B per lane) ----------
DEVINL void gload_lds16(const void* g, void* l) {
  __builtin_amdgcn_global_load_lds(
      (__attribute__((address_space(1))) void*)(g),
      (__attribute__((address_space(3))) void*)(l), 16, 0, 0);
}

DEVINL f32x4 mfma16h(f16x8 a, f16x8 b, f32x4 c) {
  return __builtin_amdgcn_mfma_f32_16x16x32_f16(a, b, c, 0, 0, 0);
}

// ================== 4-phase BK=64 fp16 GEMM core (R11 skeleton, all-plain) ==================
// C[256x256] = A * B^T, plain fp16. 8 waves 4M x 2N, wave-tile 64x128 =
// acc[4][8], BK=64. LDS: 2 buffers x {A[256][64], B[256][64]} = 128 KB.
// Rows = 128 B = 8 x 16B slots, slot XOR-swizzled by (row&7) on BOTH the
// global staging source and the ds_read address (rule 21) -> conflict-free.
// 4 phases/tile: {read B j-pair (+A at ph0) | stage half-tile | barrier |
// setprio 16 MFMA setprio | barrier}; stage B(t+1)->buf^1 at ph0/1, A(t+2)->
// buf A-region at ph2/3; counted vmcnt(4) at tile end only (T4, never 0).
// B-frag reads pipelined one phase ahead (read at p-1, consumed at p).
// A-source may span two tensors (a1 for ks<SPLIT_STEP, else a2).
// NOTE (R8 lesson): never force min-waves via __launch_bounds__ - (512,4)
// caps VGPR at 64 and spills the 128-VGPR accumulator (3 GB scratch, 5x).
template <int KSTEPS, int SPLIT_STEP>
DEVINL void gemm4p_core(const ushort_t* __restrict__ a1, const ushort_t* __restrict__ a2,
                        int lda, const ushort_t* __restrict__ bsrc, int ldb,
                        ushort_t* lds, int tid, f32x4 (&acc)[4][8]) {
  constexpr int BUF = 32768;   // elems per buffer (A 16384 + B 16384)
  constexpr int BOFF = 16384;  // B region offset (elems)
  constexpr int KM = KSTEPS - 1;
  const int lane = tid & 63, w = tid >> 6;
  const int wr = (w >> 1) * 64, wc = (w & 1) * 128;
  const int slog = (lane & 7) ^ ((lane >> 3) & 7);   // swizzled k-slot (staging)

  // ---- hoisted per-thread ds_read bases (row + swizzled slot, ks=0/1) ----
  const int sl0 = ((lane >> 4) ^ (lane & 7)) * 8;          // ks=0
  const int sl1 = ((4 + (lane >> 4)) ^ (lane & 7)) * 8;    // ks=1
  const ushort_t* dsA0 = lds + (wr + (lane & 15)) * 64 + sl0;
  const ushort_t* dsA1 = lds + (wr + (lane & 15)) * 64 + sl1;
  const ushort_t* dsB0 = lds + BOFF + (wc + (lane & 15)) * 64 + sl0;
  const ushort_t* dsB1 = lds + BOFF + (wc + (lane & 15)) * 64 + sl1;

  // ---- hoisted per-thread gload bases ----
  const size_t ldaS = (size_t)lda, ldbS = (size_t)ldb;
  const ushort_t* gA1 = a1 + (size_t)(w * 16 + (lane >> 3)) * ldaS + slog * 8;
  const ushort_t* gA2 = a2 + (size_t)(w * 16 + (lane >> 3)) * ldaS + slog * 8;
  const ushort_t* gB  = bsrc + (size_t)(w * 16 + (lane >> 3)) * ldbS + slog * 8;
  ushort_t* dA = lds + (w * 16) * 64;          // + bb*BUF + h*8192; HW adds lane*16B
  ushort_t* dB = lds + BOFF + (w * 16) * 64;

  auto stA = [&](int bb, int ks, int h) {
    const ushort_t* base = ((SPLIT_STEP >= KSTEPS) || (ks < SPLIT_STEP)) ? gA1 : gA2;
    const ushort_t* s = base + (ks & (SPLIT_STEP - 1)) * 64 + (size_t)(h * 128) * ldaS;
    ushort_t* d = dA + bb * BUF + h * 8192;
    gload_lds16(s, d);
    gload_lds16(s + 8 * ldaS, d + 512);
  };
  auto stB = [&](int bb, int ks, int h) {
    const ushort_t* s = gB + ks * 64 + (size_t)(h * 128) * ldbS;
    ushort_t* d = dB + bb * BUF + h * 8192;
    gload_lds16(s, d);
    gload_lds16(s + 8 * ldbS, d + 512);
  };

#define BAR asm volatile("s_barrier" ::: "memory")
#define RDB(J)                                              \
  Bn0 = *(const f16x8*)(rB0 + (J) * 1024);                  \
  Bn1 = *(const f16x8*)(rB1 + (J) * 1024);                  \
  Bn2 = *(const f16x8*)(rB0 + ((J) + 1) * 1024);            \
  Bn3 = *(const f16x8*)(rB1 + ((J) + 1) * 1024);
#define PHASE_MM(JP)                                        \
  __builtin_amdgcn_s_setprio(1);                            \
  _Pragma("unroll")                                         \
  for (int i = 0; i < 4; ++i) {                             \
    acc[i][2 * (JP)]     = mfma16h(rA[i][0], Bc0, acc[i][2 * (JP)]);     \
    acc[i][2 * (JP)]     = mfma16h(rA[i][1], Bc1, acc[i][2 * (JP)]);     \
    acc[i][2 * (JP) + 1] = mfma16h(rA[i][0], Bc2, acc[i][2 * (JP) + 1]); \
    acc[i][2 * (JP) + 1] = mfma16h(rA[i][1], Bc3, acc[i][2 * (JP) + 1]); \
  }                                                         \
  __builtin_amdgcn_s_setprio(0);
#define SWAPB  Bc0 = Bn0; Bc1 = Bn1; Bc2 = Bn2; Bc3 = Bn3;
#define TILE(BB, T) {                                       \
  const int ksB = ((T) + 1) & KM;                           \
  const int ksA = ((T) + 2) & KM;                           \
  const ushort_t* rA0 = dsA0 + (BB) * BUF;                  \
  const ushort_t* rA1 = dsA1 + (BB) * BUF;                  \
  const ushort_t* rB0 = dsB0 + (BB) * BUF;                  \
  const ushort_t* rB1 = dsB1 + (BB) * BUF;                  \
  f16x8 rA[4][2];                                           \
  f16x8 Bc0, Bc1, Bc2, Bc3, Bn0, Bn1, Bn2, Bn3;             \
  _Pragma("unroll")                                         \
  for (int i = 0; i < 4; ++i) {                             \
    rA[i][0] = *(const f16x8*)(rA0 + i * 1024);             \
    rA[i][1] = *(const f16x8*)(rA1 + i * 1024);             \
  }                                                         \
  Bc0 = *(const f16x8*)(rB0);                               \
  Bc1 = *(const f16x8*)(rB1);                               \
  Bc2 = *(const f16x8*)(rB0 + 1024);                        \
  Bc3 = *(const f16x8*)(rB1 + 1024);                        \
  RDB(2)                                                    \
  stB(BB ^ 1, ksB, 0);                                      \
  BAR; PHASE_MM(0) BAR;                                     \
  SWAPB RDB(4)                                              \
  stB(BB ^ 1, ksB, 1);                                      \
  BAR; PHASE_MM(1) BAR;                                     \
  SWAPB RDB(6)                                              \
  stA(BB, ksA, 0);                                          \
  BAR; PHASE_MM(2) BAR;                                     \
  SWAPB                                                     \
  stA(BB, ksA, 1);                                          \
  BAR; PHASE_MM(3)                                          \
  asm volatile("s_waitcnt vmcnt(4)" ::: "memory");          \
  BAR;                                                      \
}

  // prologue: A(0), B(0), A(1) -> vmcnt(4) leaves A(1) in flight (counted)
  stA(0, 0, 0); stA(0, 0, 1);
  stB(0, 0, 0); stB(0, 0, 1);
  stA(1, 1 & KM, 0); stA(1, 1 & KM, 1);
  asm volatile("s_waitcnt vmcnt(4)" ::: "memory");
  BAR;

  for (int t = 0; t < KSTEPS; t += 2) {
    TILE(0, t)
    TILE(1, t + 1)
  }
#undef TILE
#undef SWAPB
#undef PHASE_MM
#undef RDB
#undef BAR
}

// ---------- kernel 1: t/v/a -> plain fp16 x + transposed xT ----------
__global__ __launch_bounds__(256) void split_x_kernel(
    const float* __restrict__ v, const float* __restrict__ t, const float* __restrict__ a,
    ushort_t* __restrict__ xh, ushort_t* __restrict__ xT) {
  __shared__ ushort_t tile[64][65];
  int mod = blockIdx.z;
  const float* src = (mod == 0) ? v : (mod == 1 ? t : a);
  int b = blockIdx.y;
  int s0 = (blockIdx.x >> 4) * 64;
  int f0 = (blockIdx.x & 15) * 64;
  int tid = threadIdx.x;
  ushort_t* xp = xh + mod * NX;
  ushort_t* xt = xT + mod * NX;
  int fl = (tid & 15) * 4;
#pragma unroll
  for (int r = 0; r < 4; ++r) {
    int sl = (tid >> 4) + r * 16;
    int row = b * S + s0 + sl;
    float4 x = *(const float4*)(src + (size_t)row * F + f0 + fl);
    ushort_t h0 = f2h(x.x), h1 = f2h(x.y), h2 = f2h(x.z), h3 = f2h(x.w);
    *(ushort4*)(xp + (size_t)row * F + f0 + fl) = make_ushort4(h0, h1, h2, h3);
    tile[sl][fl] = h0; tile[sl][fl + 1] = h1; tile[sl][fl + 2] = h2; tile[sl][fl + 3] = h3;
  }
  __syncthreads();
#pragma unroll
  for (int r = 0; r < 4; ++r) {
    int flr = (tid >> 4) + r * 16;
    int sl4 = (tid & 15) * 4;
    ushort4 o = make_ushort4(tile[sl4][flr], tile[sl4 + 1][flr],
                             tile[sl4 + 2][flr], tile[sl4 + 3][flr]);
    size_t tidx = ((size_t)(b * F + f0 + flr)) * S + s0 + sl4;
    *(ushort4*)(xt + tidx) = o;
  }
}

// ---------- kernel 2: W (2048x1024) -> WT plain fp16 (1024 rows x K=2048) ----------
__global__ __launch_bounds__(256) void split_w_kernel(
    const float* __restrict__ w0, const float* __restrict__ w1, const float* __restrict__ w2,
    ushort_t* __restrict__ wtpack) {
  __shared__ ushort_t th[64][65];
  int br = blockIdx.z;
  const float* w = (br == 0) ? w0 : (br == 1 ? w1 : w2);
  int g0 = blockIdx.x * 64;
  int f0 = blockIdx.y * 64;
  int tid = threadIdx.x;
  int gl = (tid & 15) * 4;
#pragma unroll
  for (int r = 0; r < 4; ++r) {
    int fl = (tid >> 4) + r * 16;
    float4 x = *(const float4*)(w + (size_t)(f0 + fl) * F + g0 + gl);
    th[fl][gl] = f2h(x.x); th[fl][gl + 1] = f2h(x.y);
    th[fl][gl + 2] = f2h(x.z); th[fl][gl + 3] = f2h(x.w);
  }
  __syncthreads();
  ushort_t* op = wtpack + br * NW;
#pragma unroll
  for (int r = 0; r < 4; ++r) {
    int glr = (tid >> 4) + r * 16;
    int fl4 = (tid & 15) * 4;
    size_t o = (size_t)(g0 + glr) * (2 * F) + f0 + fl4;
    *(ushort4*)(op + o) = make_ushort4(th[fl4][glr], th[fl4 + 1][glr],
                                       th[fl4 + 2][glr], th[fl4 + 3][glr]);
  }
}

// ---------- kernel 3: Feat = tanh(concat(x1,x2) @ W + b), fp16 out ----------
__global__ __launch_bounds__(512, 2) void feat_gemm_kernel(
    const ushort_t* __restrict__ xh, const ushort_t* __restrict__ wtpack,
    const float* __restrict__ b0, const float* __restrict__ b1, const float* __restrict__ b2,
    ushort_t* __restrict__ fpack) {
  constexpr int M1[3] = {1, 1, 2};   // t, t, a
  constexpr int M2[3] = {0, 2, 0};   // v, a, v
  __shared__ __attribute__((aligned(16))) ushort_t lds[2 * 32768];   // 128 KB
  int br = blockIdx.z;
  int lin = blockIdx.x;              // 0..127
  // XCD-chunked: lin&7 = XCD; 4 gn-blocks sharing an A-panel-pair same XCD.
  int gm0 = ((lin & 7) * 4 + ((lin >> 3) & 3)) * 256;
  int gn0 = (lin >> 5) * 256;
  int tid = threadIdx.x, lane = tid & 63, w = tid >> 6;
  const ushort_t* a1 = xh + M1[br] * NX + (size_t)gm0 * F;
  const ushort_t* a2 = xh + M2[br] * NX + (size_t)gm0 * F;
  const ushort_t* bb = wtpack + br * NW + (size_t)gn0 * (2 * F);
  f32x4 acc[4][8] = {};
  gemm4p_core<32, 16>(a1, a2, F, bb, 2 * F, lds, tid, acc);
  const float* bias = (br == 0) ? b0 : (br == 1 ? b1 : b2);
  ushort_t* op = fpack + br * NX;
  int wr = (w >> 1) * 64, wc = (w & 1) * 128;
#pragma unroll
  for (int i = 0; i < 4; ++i)
#pragma unroll
    for (int j = 0; j < 8; ++j)
#pragma unroll
      for (int r = 0; r < 4; ++r) {
        int row = gm0 + wr + i * 16 + (lane >> 4) * 4 + r;
        int col = gn0 + wc + j * 16 + (lane & 15);
        op[(size_t)row * F + col] = f2h(tanhf(acc[i][j][r] + bias[col]));
      }
}

// ---------- kernel 4: scores = q @ feat^T, fp32 out (plain fp16, 4p core) ----------
__global__ __launch_bounds__(512, 2) void scores_gemm_kernel(
    const ushort_t* __restrict__ xh, const ushort_t* __restrict__ fpack,
    float* __restrict__ scores) {
  constexpr int QM[3] = {2, 0, 1};   // a, v, t
  __shared__ __attribute__((aligned(16))) ushort_t lds[2 * 32768];   // 128 KB
  int z = blockIdx.z;
  int br = z >> 4, b = z & 15;
  int gm0 = blockIdx.x * 256;
  int gn0 = blockIdx.y * 256;
  int tid = threadIdx.x, lane = tid & 63, w = tid >> 6;
  const ushort_t* a1 = xh + QM[br] * NX + (size_t)(b * S + gm0) * F;
  const ushort_t* bb = fpack + br * NX + (size_t)(b * S + gn0) * F;
  f32x4 acc[4][8] = {};
  gemm4p_core<16, 16>(a1, a1, F, bb, F, lds, tid, acc);
  float* out = scores + (size_t)z * S * S;
  int wr = (w >> 1) * 64, wc = (w & 1) * 128;
#pragma unroll
  for (int i = 0; i < 4; ++i)
#pragma unroll
    for (int j = 0; j < 8; ++j)
#pragma unroll
      for (int r = 0; r < 4; ++r) {
        int row = gm0 + wr + i * 16 + (lane >> 4) * 4 + r;
        int col = gn0 + wc + j * 16 + (lane & 15);
        out[(size_t)row * S + col] = acc[i][j][r];
      }
}

// ---------- kernel 5: row softmax (512), fp32 in -> fp16 p ----------
__global__ __launch_bounds__(256) void softmax_kernel(
    const float* __restrict__ scores, ushort_t* __restrict__ p) {
  int wave = threadIdx.x >> 6, lane = threadIdx.x & 63;
  int row = blockIdx.x * 4 + wave;
  const float* src = scores + (size_t)row * S;
  float4 v0 = *(const float4*)(src + lane * 8);
  float4 v1 = *(const float4*)(src + lane * 8 + 4);
  float m = fmaxf(fmaxf(fmaxf(v0.x, v0.y), fmaxf(v0.z, v0.w)),
                  fmaxf(fmaxf(v1.x, v1.y), fmaxf(v1.z, v1.w)));
#pragma unroll
  for (int d = 1; d < 64; d <<= 1) m = fmaxf(m, __shfl_xor(m, d));
  float e[8] = {expf(v0.x - m), expf(v0.y - m), expf(v0.z - m), expf(v0.w - m),
                expf(v1.x - m), expf(v1.y - m), expf(v1.z - m), expf(v1.w - m)};
  float s = ((e[0] + e[1]) + (e[2] + e[3])) + ((e[4] + e[5]) + (e[6] + e[7]));
#pragma unroll
  for (int d = 1; d < 64; d <<= 1) s += __shfl_xor(s, d);
  float inv = 1.0f / s;
  u16x8 o;
#pragma unroll
  for (int j = 0; j < 8; ++j) o[j] = f2h(e[j] * inv);
  *(u16x8*)(p + (size_t)row * S + lane * 8) = o;
}

// ---------- kernel 6: O = (p @ q) * feat, fp32 out ----------
__global__ __launch_bounds__(512, 2) void pv_gemm_kernel(
    const ushort_t* __restrict__ p, const ushort_t* __restrict__ xT,
    const ushort_t* __restrict__ fpack, float* __restrict__ out) {
  constexpr int QM[3] = {2, 0, 1};
  __shared__ __attribute__((aligned(16))) ushort_t lds[2 * 32768];   // 128 KB
  int z = blockIdx.z;
  int br = z >> 4, b = z & 15;
  int gm0 = blockIdx.x * 256;
  int gn0 = blockIdx.y * 256;
  int tid = threadIdx.x, lane = tid & 63, w = tid >> 6;
  const ushort_t* pa = p + (size_t)z * S * S + (size_t)gm0 * S;
  const ushort_t* qt = xT + QM[br] * NX + (size_t)b * F * S + (size_t)gn0 * S;  // [f][s]
  f32x4 acc[4][8] = {};
  gemm4p_core<8, 8>(pa, pa, S, qt, S, lds, tid, acc);
  const ushort_t* fp = fpack + br * NX;
  int wr = (w >> 1) * 64, wc = (w & 1) * 128;
#pragma unroll
  for (int i = 0; i < 4; ++i)
#pragma unroll
    for (int j = 0; j < 8; ++j)
#pragma unroll
      for (int r = 0; r < 4; ++r) {
        int row = gm0 + wr + i * 16 + (lane >> 4) * 4 + r;
        int col = gn0 + wc + j * 16 + (lane & 15);
        float fe = h2f(fp[(size_t)(b * S + row) * F + col]);
        out[(size_t)(b * S + row) * (3 * F) + br * F + col] = acc[i][j][r] * fe;
      }
}

extern "C" void kernel_launch(void* const* d_in, const int* in_sizes, int n_in,
                              void* d_out, int out_size, void* d_ws, size_t ws_size,
                              hipStream_t stream) {
  (void)in_sizes; (void)n_in; (void)out_size; (void)ws_size;
  const float* v = (const float*)d_in[0];
  const float* t = (const float*)d_in[1];
  const float* a = (const float*)d_in[2];
  const float* W_tv = (const float*)d_in[3];
  const float* b_tv = (const float*)d_in[4];
  const float* W_ta = (const float*)d_in[5];
  const float* b_ta = (const float*)d_in[6];
  const float* W_av = (const float*)d_in[7];
  const float* b_av = (const float*)d_in[8];
  float* out = (float*)d_out;

  // ws layout (~230 MB total)
  ushort_t* xh = (ushort_t*)d_ws;               // 3 * NX (fp16 plain)
  ushort_t* xT = xh + 3 * NX;                   // 3 * NX (fp16 plain, [f][s])
  ushort_t* wtpack = xT + 3 * NX;               // 3 * NW (fp16 plain)
  ushort_t* fpack = wtpack + 3 * NW;            // 3 * NX (fp16 plain)
  float* scores = (float*)(fpack + 3 * NX);
  ushort_t* pbuf = (ushort_t*)(scores + NSC);

  split_x_kernel<<<dim3(128, 16, 3), 256, 0, stream>>>(v, t, a, xh, xT);
  split_w_kernel<<<dim3(16, 32, 3), 256, 0, stream>>>(W_tv, W_ta, W_av, wtpack);
  feat_gemm_kernel<<<dim3(128, 1, 3), 512, 0, stream>>>(xh, wtpack,
                                                        b_tv, b_ta, b_av, fpack);
  scores_gemm_kernel<<<dim3(2, 2, 48), 512, 0, stream>>>(xh, fpack, scores);
  softmax_kernel<<<dim3((3 * B * S) / 4), 256, 0, stream>>>(scores, pbuf);
  pv_gemm_kernel<<<dim3(2, 4, 48), 512, 0, stream>>>(pbuf, xT, fpack, out);
}

// Round 13
// 289.939 us; speedup vs baseline: 5.8357x; 1.0182x over previous
//
#include <hip/hip_runtime.h>

typedef unsigned short ushort_t;
typedef _Float16 f16x8 __attribute__((ext_vector_type(8)));
typedef float f32x4 __attribute__((ext_vector_type(4)));
typedef unsigned short u16x8 __attribute__((ext_vector_type(8)));

#define DEVINL __device__ __forceinline__

constexpr int B = 16, S = 512, F = 1024;
constexpr int M_ROWS = B * S;                    // 8192
constexpr size_t NX = (size_t)M_ROWS * F;        // 8,388,608 elems per modality
constexpr size_t NW = (size_t)F * (2 * F);       // 2,097,152 elems per branch

// ---------- fp16 helpers ----------
DEVINL ushort_t f2h(float f) { return __builtin_bit_cast(ushort_t, (_Float16)f); }
DEVINL float h2f(ushort_t h) { return (float)__builtin_bit_cast(_Float16, h); }

// ---------- async global->LDS (16B per lane) ----------
DEVINL void gload_lds16(const void* g, void* l) {
  __builtin_amdgcn_global_load_lds(
      (__attribute__((address_space(1))) void*)(g),
      (__attribute__((address_space(3))) void*)(l), 16, 0, 0);
}

DEVINL f32x4 mfma16h(f16x8 a, f16x8 b, f32x4 c) {
  return __builtin_amdgcn_mfma_f32_16x16x32_f16(a, b, c, 0, 0, 0);
}

// ================== 4-phase BK=64 fp16 GEMM core (R11/R12, unchanged) ==================
// NOTE (R8 lesson): never force min-waves via __launch_bounds__ — (512,4)
// caps VGPR at 64 and spills the 128-VGPR accumulator (3 GB scratch, 5x).
template <int KSTEPS, int SPLIT_STEP>
DEVINL void gemm4p_core(const ushort_t* __restrict__ a1, const ushort_t* __restrict__ a2,
                        int lda, const ushort_t* __restrict__ bsrc, int ldb,
                        ushort_t* lds, int tid, f32x4 (&acc)[4][8]) {
  constexpr int BUF = 32768;   // elems per buffer (A 16384 + B 16384)
  constexpr int BOFF = 16384;  // B region offset (elems)
  constexpr int KM = KSTEPS - 1;
  const int lane = tid & 63, w = tid >> 6;
  const int wr = (w >> 1) * 64, wc = (w & 1) * 128;
  const int slog = (lane & 7) ^ ((lane >> 3) & 7);   // swizzled k-slot (staging)

  const int sl0 = ((lane >> 4) ^ (lane & 7)) * 8;          // ks=0
  const int sl1 = ((4 + (lane >> 4)) ^ (lane & 7)) * 8;    // ks=1
  const ushort_t* dsA0 = lds + (wr + (lane & 15)) * 64 + sl0;
  const ushort_t* dsA1 = lds + (wr + (lane & 15)) * 64 + sl1;
  const ushort_t* dsB0 = lds + BOFF + (wc + (lane & 15)) * 64 + sl0;
  const ushort_t* dsB1 = lds + BOFF + (wc + (lane & 15)) * 64 + sl1;

  const size_t ldaS = (size_t)lda, ldbS = (size_t)ldb;
  const ushort_t* gA1 = a1 + (size_t)(w * 16 + (lane >> 3)) * ldaS + slog * 8;
  const ushort_t* gA2 = a2 + (size_t)(w * 16 + (lane >> 3)) * ldaS + slog * 8;
  const ushort_t* gB  = bsrc + (size_t)(w * 16 + (lane >> 3)) * ldbS + slog * 8;
  ushort_t* dA = lds + (w * 16) * 64;
  ushort_t* dB = lds + BOFF + (w * 16) * 64;

  auto stA = [&](int bb, int ks, int h) {
    const ushort_t* base = ((SPLIT_STEP >= KSTEPS) || (ks < SPLIT_STEP)) ? gA1 : gA2;
    const ushort_t* s = base + (ks & (SPLIT_STEP - 1)) * 64 + (size_t)(h * 128) * ldaS;
    ushort_t* d = dA + bb * BUF + h * 8192;
    gload_lds16(s, d);
    gload_lds16(s + 8 * ldaS, d + 512);
  };
  auto stB = [&](int bb, int ks, int h) {
    const ushort_t* s = gB + ks * 64 + (size_t)(h * 128) * ldbS;
    ushort_t* d = dB + bb * BUF + h * 8192;
    gload_lds16(s, d);
    gload_lds16(s + 8 * ldbS, d + 512);
  };

#define BAR asm volatile("s_barrier" ::: "memory")
#define RDB(J)                                              \
  Bn0 = *(const f16x8*)(rB0 + (J) * 1024);                  \
  Bn1 = *(const f16x8*)(rB1 + (J) * 1024);                  \
  Bn2 = *(const f16x8*)(rB0 + ((J) + 1) * 1024);            \
  Bn3 = *(const f16x8*)(rB1 + ((J) + 1) * 1024);
#define PHASE_MM(JP)                                        \
  __builtin_amdgcn_s_setprio(1);                            \
  _Pragma("unroll")                                         \
  for (int i = 0; i < 4; ++i) {                             \
    acc[i][2 * (JP)]     = mfma16h(rA[i][0], Bc0, acc[i][2 * (JP)]);     \
    acc[i][2 * (JP)]     = mfma16h(rA[i][1], Bc1, acc[i][2 * (JP)]);     \
    acc[i][2 * (JP) + 1] = mfma16h(rA[i][0], Bc2, acc[i][2 * (JP) + 1]); \
    acc[i][2 * (JP) + 1] = mfma16h(rA[i][1], Bc3, acc[i][2 * (JP) + 1]); \
  }                                                         \
  __builtin_amdgcn_s_setprio(0);
#define SWAPB  Bc0 = Bn0; Bc1 = Bn1; Bc2 = Bn2; Bc3 = Bn3;
#define TILE(BB, T) {                                       \
  const int ksB = ((T) + 1) & KM;                           \
  const int ksA = ((T) + 2) & KM;                           \
  const ushort_t* rA0 = dsA0 + (BB) * BUF;                  \
  const ushort_t* rA1 = dsA1 + (BB) * BUF;                  \
  const ushort_t* rB0 = dsB0 + (BB) * BUF;                  \
  const ushort_t* rB1 = dsB1 + (BB) * BUF;                  \
  f16x8 rA[4][2];                                           \
  f16x8 Bc0, Bc1, Bc2, Bc3, Bn0, Bn1, Bn2, Bn3;             \
  _Pragma("unroll")                                         \
  for (int i = 0; i < 4; ++i) {                             \
    rA[i][0] = *(const f16x8*)(rA0 + i * 1024);             \
    rA[i][1] = *(const f16x8*)(rA1 + i * 1024);             \
  }                                                         \
  Bc0 = *(const f16x8*)(rB0);                               \
  Bc1 = *(const f16x8*)(rB1);                               \
  Bc2 = *(const f16x8*)(rB0 + 1024);                        \
  Bc3 = *(const f16x8*)(rB1 + 1024);                        \
  RDB(2)                                                    \
  stB(BB ^ 1, ksB, 0);                                      \
  BAR; PHASE_MM(0) BAR;                                     \
  SWAPB RDB(4)                                              \
  stB(BB ^ 1, ksB, 1);                                      \
  BAR; PHASE_MM(1) BAR;                                     \
  SWAPB RDB(6)                                              \
  stA(BB, ksA, 0);                                          \
  BAR; PHASE_MM(2) BAR;                                     \
  SWAPB                                                     \
  stA(BB, ksA, 1);                                          \
  BAR; PHASE_MM(3)                                          \
  asm volatile("s_waitcnt vmcnt(4)" ::: "memory");          \
  BAR;                                                      \
}

  stA(0, 0, 0); stA(0, 0, 1);
  stB(0, 0, 0); stB(0, 0, 1);
  stA(1, 1 & KM, 0); stA(1, 1 & KM, 1);
  asm volatile("s_waitcnt vmcnt(4)" ::: "memory");
  BAR;

  for (int t = 0; t < KSTEPS; t += 2) {
    TILE(0, t)
    TILE(1, t + 1)
  }
#undef TILE
#undef SWAPB
#undef PHASE_MM
#undef RDB
#undef BAR
}

// ---------- kernel 1: t/v/a -> plain fp16 x + transposed xT ----------
__global__ __launch_bounds__(256) void split_x_kernel(
    const float* __restrict__ v, const float* __restrict__ t, const float* __restrict__ a,
    ushort_t* __restrict__ xh, ushort_t* __restrict__ xT) {
  __shared__ ushort_t tile[64][65];
  int mod = blockIdx.z;
  const float* src = (mod == 0) ? v : (mod == 1 ? t : a);
  int b = blockIdx.y;
  int s0 = (blockIdx.x >> 4) * 64;
  int f0 = (blockIdx.x & 15) * 64;
  int tid = threadIdx.x;
  ushort_t* xp = xh + mod * NX;
  ushort_t* xt = xT + mod * NX;
  int fl = (tid & 15) * 4;
#pragma unroll
  for (int r = 0; r < 4; ++r) {
    int sl = (tid >> 4) + r * 16;
    int row = b * S + s0 + sl;
    float4 x = *(const float4*)(src + (size_t)row * F + f0 + fl);
    ushort_t h0 = f2h(x.x), h1 = f2h(x.y), h2 = f2h(x.z), h3 = f2h(x.w);
    *(ushort4*)(xp + (size_t)row * F + f0 + fl) = make_ushort4(h0, h1, h2, h3);
    tile[sl][fl] = h0; tile[sl][fl + 1] = h1; tile[sl][fl + 2] = h2; tile[sl][fl + 3] = h3;
  }
  __syncthreads();
#pragma unroll
  for (int r = 0; r < 4; ++r) {
    int flr = (tid >> 4) + r * 16;
    int sl4 = (tid & 15) * 4;
    ushort4 o = make_ushort4(tile[sl4][flr], tile[sl4 + 1][flr],
                             tile[sl4 + 2][flr], tile[sl4 + 3][flr]);
    size_t tidx = ((size_t)(b * F + f0 + flr)) * S + s0 + sl4;
    *(ushort4*)(xt + tidx) = o;
  }
}

// ---------- kernel 2: W (2048x1024) -> WT plain fp16 (1024 rows x K=2048) ----------
__global__ __launch_bounds__(256) void split_w_kernel(
    const float* __restrict__ w0, const float* __restrict__ w1, const float* __restrict__ w2,
    ushort_t* __restrict__ wtpack) {
  __shared__ ushort_t th[64][65];
  int br = blockIdx.z;
  const float* w = (br == 0) ? w0 : (br == 1 ? w1 : w2);
  int g0 = blockIdx.x * 64;
  int f0 = blockIdx.y * 64;
  int tid = threadIdx.x;
  int gl = (tid & 15) * 4;
#pragma unroll
  for (int r = 0; r < 4; ++r) {
    int fl = (tid >> 4) + r * 16;
    float4 x = *(const float4*)(w + (size_t)(f0 + fl) * F + g0 + gl);
    th[fl][gl] = f2h(x.x); th[fl][gl + 1] = f2h(x.y);
    th[fl][gl + 2] = f2h(x.z); th[fl][gl + 3] = f2h(x.w);
  }
  __syncthreads();
  ushort_t* op = wtpack + br * NW;
#pragma unroll
  for (int r = 0; r < 4; ++r) {
    int glr = (tid >> 4) + r * 16;
    int fl4 = (tid & 15) * 4;
    size_t o = (size_t)(g0 + glr) * (2 * F) + f0 + fl4;
    *(ushort4*)(op + o) = make_ushort4(th[fl4][glr], th[fl4 + 1][glr],
                                       th[fl4 + 2][glr], th[fl4 + 3][glr]);
  }
}

// ---------- kernel 3: Feat = tanh(concat(x1,x2) @ W + b), fp16 out ----------
__global__ __launch_bounds__(512, 2) void feat_gemm_kernel(
    const ushort_t* __restrict__ xh, const ushort_t* __restrict__ wtpack,
    const float* __restrict__ b0, const float* __restrict__ b1, const float* __restrict__ b2,
    ushort_t* __restrict__ fpack) {
  constexpr int M1[3] = {1, 1, 2};   // t, t, a
  constexpr int M2[3] = {0, 2, 0};   // v, a, v
  __shared__ __attribute__((aligned(16))) ushort_t lds[2 * 32768];   // 128 KB
  int br = blockIdx.z;
  int lin = blockIdx.x;              // 0..127
  int gm0 = ((lin & 7) * 4 + ((lin >> 3) & 3)) * 256;
  int gn0 = (lin >> 5) * 256;
  int tid = threadIdx.x, lane = tid & 63, w = tid >> 6;
  const ushort_t* a1 = xh + M1[br] * NX + (size_t)gm0 * F;
  const ushort_t* a2 = xh + M2[br] * NX + (size_t)gm0 * F;
  const ushort_t* bb = wtpack + br * NW + (size_t)gn0 * (2 * F);
  f32x4 acc[4][8] = {};
  gemm4p_core<32, 16>(a1, a2, F, bb, 2 * F, lds, tid, acc);
  const float* bias = (br == 0) ? b0 : (br == 1 ? b1 : b2);
  ushort_t* op = fpack + br * NX;
  int wr = (w >> 1) * 64, wc = (w & 1) * 128;
#pragma unroll
  for (int i = 0; i < 4; ++i)
#pragma unroll
    for (int j = 0; j < 8; ++j)
#pragma unroll
      for (int r = 0; r < 4; ++r) {
        int row = gm0 + wr + i * 16 + (lane >> 4) * 4 + r;
        int col = gn0 + wc + j * 16 + (lane & 15);
        op[(size_t)row * F + col] = f2h(tanhf(acc[i][j][r] + bias[col]));
      }
}

// ---------- kernel 4: fused scores+softmax -> P fp16 ----------
// Tile 128 q-rows x 512 keys (full score rows in-register -> softmax in
// epilogue). 8 waves 2M x 4N, wave-tile 64x128 = acc[4][8]. BK=32, 3-buffer
// barrier-light K-loop (R5-proven skeleton): depth-2 prefetch, counted
// vmcnt(5)/step (1 A-gload + 4 B-gloads per wave), XOR-swizzled staging
// source + ds_read (rule 21). Epilogue: row-max via j-local + 4x shfl_xor
// (16-lane col group) + 4-wave LDS partial reduce; exp/sum likewise; P fp16.
__global__ __launch_bounds__(512, 2) void attn_scores_kernel(
    const ushort_t* __restrict__ xh, const ushort_t* __restrict__ fpack,
    ushort_t* __restrict__ pbuf) {
  constexpr int QM[3] = {2, 0, 1};   // a, v, t
  constexpr int BUFE = 20480;        // elems: A 128x32=4096, B 512x32=16384
  constexpr int BOFFE = 4096;
  __shared__ __attribute__((aligned(16))) ushort_t lds[3 * BUFE + 1024];  // +2KB red
  float* redm = (float*)(lds + 3 * BUFE);   // [4 wn][128 rows]
  int z = blockIdx.z;
  int br = z >> 4, b = z & 15;
  int gm0 = blockIdx.x * 128;
  int tid = threadIdx.x, lane = tid & 63, w = tid >> 6;
  int wm = w >> 2, wn = w & 3;
  int wr = wm * 64, wc = wn * 128;
  const ushort_t* qa = xh + QM[br] * NX + (size_t)(b * S + gm0) * F;
  const ushort_t* kb = fpack + br * NX + (size_t)(b * S) * F;   // all 512 key rows

  const int scol = (((lane & 3) ^ ((lane >> 3) & 3)) * 8);
  const int foff = (lane & 15) * 32 + (((lane >> 4) ^ ((lane >> 1) & 3)) * 8);

  auto stA = [&](int sb, int ks) {
    const ushort_t* s = qa + (size_t)(w * 16 + (lane >> 2)) * F + ks * 32 + scol;
    gload_lds16(s, lds + sb * BUFE + w * 512);
  };
  auto stB = [&](int sb, int ks) {
#pragma unroll
    for (int g = 0; g < 4; ++g) {
      const ushort_t* s = kb + (size_t)(w * 64 + g * 16 + (lane >> 2)) * F + ks * 32 + scol;
      gload_lds16(s, lds + sb * BUFE + BOFFE + w * 2048 + g * 512);
    }
  };

  f32x4 acc[4][8] = {};
  // prologue: stage steps 0,1
  stA(0, 0); stB(0, 0);
  stA(1, 1); stB(1, 1);
  asm volatile("s_waitcnt vmcnt(5)" ::: "memory");
  asm volatile("s_barrier" ::: "memory");

  for (int t = 0; t < 32; ++t) {
    const int cb = t % 3, sb = (t + 2) % 3;
    const int ks = (t + 2) & 31;                 // clamped tail: uniform vmcnt
    stA(sb, ks); stB(sb, ks);
    const ushort_t* L = lds + cb * BUFE;
    f16x8 rA[4], rB[8];
#pragma unroll
    for (int i = 0; i < 4; ++i) rA[i] = *(const f16x8*)(L + (wr + i * 16) * 32 + foff);
#pragma unroll
    for (int j = 0; j < 8; ++j)
      rB[j] = *(const f16x8*)(L + BOFFE + (wc + j * 16) * 32 + foff);
    __builtin_amdgcn_s_setprio(1);
#pragma unroll
    for (int j = 0; j < 8; ++j)
#pragma unroll
      for (int i = 0; i < 4; ++i) acc[i][j] = mfma16h(rA[i], rB[j], acc[i][j]);
    __builtin_amdgcn_s_setprio(0);
    asm volatile("s_waitcnt vmcnt(5)" ::: "memory");
    asm volatile("s_barrier" ::: "memory");
  }

  // ---- softmax epilogue over the 512 cols ----
  // pass 1: row max (local over j, shfl over 16-lane col group, LDS over wn)
  float mx[4][4];
#pragma unroll
  for (int i = 0; i < 4; ++i)
#pragma unroll
    for (int r = 0; r < 4; ++r) {
      float m = acc[i][0][r];
#pragma unroll
      for (int j = 1; j < 8; ++j) m = fmaxf(m, acc[i][j][r]);
#pragma unroll
      for (int d = 1; d < 16; d <<= 1) m = fmaxf(m, __shfl_xor(m, d));
      mx[i][r] = m;
    }
  if ((lane & 15) == 0) {
#pragma unroll
    for (int i = 0; i < 4; ++i)
#pragma unroll
      for (int r = 0; r < 4; ++r)
        redm[wn * 128 + wr + i * 16 + (lane >> 4) * 4 + r] = mx[i][r];
  }
  __syncthreads();
  float inv[4][4];
#pragma unroll
  for (int i = 0; i < 4; ++i)
#pragma unroll
    for (int r = 0; r < 4; ++r) {
      int row = wr + i * 16 + (lane >> 4) * 4 + r;
      float fm = fmaxf(fmaxf(redm[row], redm[128 + row]),
                       fmaxf(redm[256 + row], redm[384 + row]));
      float s = 0.f;
#pragma unroll
      for (int j = 0; j < 8; ++j) {
        float e = expf(acc[i][j][r] - fm);
        acc[i][j][r] = e;
        s += e;
      }
#pragma unroll
      for (int d = 1; d < 16; d <<= 1) s += __shfl_xor(s, d);
      inv[i][r] = s;   // stash partial-complete sum (same in all 16 lanes)
    }
  __syncthreads();     // all reads of max partials done before overwrite
  if ((lane & 15) == 0) {
#pragma unroll
    for (int i = 0; i < 4; ++i)
#pragma unroll
      for (int r = 0; r < 4; ++r)
        redm[wn * 128 + wr + i * 16 + (lane >> 4) * 4 + r] = inv[i][r];
  }
  __syncthreads();
  ushort_t* pout = pbuf + (size_t)z * S * S;
#pragma unroll
  for (int i = 0; i < 4; ++i)
#pragma unroll
    for (int r = 0; r < 4; ++r) {
      int row = wr + i * 16 + (lane >> 4) * 4 + r;
      float fs = (redm[row] + redm[128 + row]) + (redm[256 + row] + redm[384 + row]);
      float fi = 1.0f / fs;
#pragma unroll
      for (int j = 0; j < 8; ++j) {
        int col = wc + j * 16 + (lane & 15);
        pout[(size_t)(gm0 + row) * S + col] = f2h(acc[i][j][r] * fi);
      }
    }
}

// ---------- kernel 6: O = (p @ q) * feat, fp32 out ----------
__global__ __launch_bounds__(512, 2) void pv_gemm_kernel(
    const ushort_t* __restrict__ p, const ushort_t* __restrict__ xT,
    const ushort_t* __restrict__ fpack, float* __restrict__ out) {
  constexpr int QM[3] = {2, 0, 1};
  __shared__ __attribute__((aligned(16))) ushort_t lds[2 * 32768];   // 128 KB
  int z = blockIdx.z;
  int br = z >> 4, b = z & 15;
  int gm0 = blockIdx.x * 256;
  int gn0 = blockIdx.y * 256;
  int tid = threadIdx.x, lane = tid & 63, w = tid >> 6;
  const ushort_t* pa = p + (size_t)z * S * S + (size_t)gm0 * S;
  const ushort_t* qt = xT + QM[br] * NX + (size_t)b * F * S + (size_t)gn0 * S;  // [f][s]
  f32x4 acc[4][8] = {};
  gemm4p_core<8, 8>(pa, pa, S, qt, S, lds, tid, acc);
  const ushort_t* fp = fpack + br * NX;
  int wr = (w >> 1) * 64, wc = (w & 1) * 128;
#pragma unroll
  for (int i = 0; i < 4; ++i)
#pragma unroll
    for (int j = 0; j < 8; ++j)
#pragma unroll
      for (int r = 0; r < 4; ++r) {
        int row = gm0 + wr + i * 16 + (lane >> 4) * 4 + r;
        int col = gn0 + wc + j * 16 + (lane & 15);
        float fe = h2f(fp[(size_t)(b * S + row) * F + col]);
        out[(size_t)(b * S + row) * (3 * F) + br * F + col] = acc[i][j][r] * fe;
      }
}

extern "C" void kernel_launch(void* const* d_in, const int* in_sizes, int n_in,
                              void* d_out, int out_size, void* d_ws, size_t ws_size,
                              hipStream_t stream) {
  (void)in_sizes; (void)n_in; (void)out_size; (void)ws_size;
  const float* v = (const float*)d_in[0];
  const float* t = (const float*)d_in[1];
  const float* a = (const float*)d_in[2];
  const float* W_tv = (const float*)d_in[3];
  const float* b_tv = (const float*)d_in[4];
  const float* W_ta = (const float*)d_in[5];
  const float* b_ta = (const float*)d_in[6];
  const float* W_av = (const float*)d_in[7];
  const float* b_av = (const float*)d_in[8];
  float* out = (float*)d_out;

  // ws layout (~190 MB total; no fp32 scores buffer)
  ushort_t* xh = (ushort_t*)d_ws;               // 3 * NX (fp16 plain)
  ushort_t* xT = xh + 3 * NX;                   // 3 * NX (fp16 plain, [f][s])
  ushort_t* wtpack = xT + 3 * NX;               // 3 * NW (fp16 plain)
  ushort_t* fpack = wtpack + 3 * NW;            // 3 * NX (fp16 plain)
  ushort_t* pbuf = fpack + 3 * NX;              // 3*B*S*S (fp16)

  split_x_kernel<<<dim3(128, 16, 3), 256, 0, stream>>>(v, t, a, xh, xT);
  split_w_kernel<<<dim3(16, 32, 3), 256, 0, stream>>>(W_tv, W_ta, W_av, wtpack);
  feat_gemm_kernel<<<dim3(128, 1, 3), 512, 0, stream>>>(xh, wtpack,
                                                        b_tv, b_ta, b_av, fpack);
  attn_scores_kernel<<<dim3(4, 1, 48), 512, 0, stream>>>(xh, fpack, pbuf);
  pv_gemm_kernel<<<dim3(2, 4, 48), 512, 0, stream>>>(pbuf, xT, fpack, out);
}